// Round 1
// baseline (528.969 us; speedup 1.0000x reference)
//
#include <hip/hip_runtime.h>
#include <math.h>

#define T 2048
#define HID 2048
#define NH 32
#define NKV 4
#define HD 128
#define QKV_DIM 5120   // (NH + 2*NKV) * HD
#define OD 4096        // NH * HD
#define SCALE 0.08838834764831845f

typedef _Float16 half8 __attribute__((ext_vector_type(8)));
typedef _Float16 half4v __attribute__((ext_vector_type(4)));
typedef float floatx4 __attribute__((ext_vector_type(4)));

// ---------------- fp32 -> fp16 conversion ----------------
__global__ __launch_bounds__(256)
void cvt_f16(const float* __restrict__ in, _Float16* __restrict__ out, int n) {
    int i = (blockIdx.x * 256 + threadIdx.x) * 4;
    if (i < n) {
        float4 v = *(const float4*)(in + i);
        half4v o = { (_Float16)v.x, (_Float16)v.y, (_Float16)v.z, (_Float16)v.w };
        *(half4v*)(out + i) = o;
    }
}

// ---------------- GEMM (NT): C[M,N] fp32 = A[M,K] * B[N,K]^T, fp16 MFMA ---
// 64x64 tile, BK=32, 256 threads = 4 waves, each wave a 32x32 quadrant.
__global__ __launch_bounds__(256)
void gemm_nt(const _Float16* __restrict__ A, const _Float16* __restrict__ B,
             float* __restrict__ C, int M, int N, int K) {
    __shared__ __align__(16) _Float16 Asm[64][40];  // +8 pad breaks pow2 stride
    __shared__ __align__(16) _Float16 Bsm[64][40];
    int tid  = threadIdx.x;
    int wave = tid >> 6, lane = tid & 63;
    int quad = lane >> 4, l16 = lane & 15;
    int m0 = blockIdx.y * 64, n0 = blockIdx.x * 64;
    int wm = (wave >> 1) * 32, wn = (wave & 1) * 32;
    int lr = tid >> 2;          // staging row 0..63
    int lc = (tid & 3) * 8;     // staging k-offset {0,8,16,24}
    floatx4 acc00 = {}, acc01 = {}, acc10 = {}, acc11 = {};

    for (int k0 = 0; k0 < K; k0 += 32) {
        __syncthreads();
        *(half8*)&Asm[lr][lc] = *(const half8*)&A[(size_t)(m0 + lr) * K + k0 + lc];
        *(half8*)&Bsm[lr][lc] = *(const half8*)&B[(size_t)(n0 + lr) * K + k0 + lc];
        __syncthreads();
        half8 a0 = *(const half8*)&Asm[wm + l16][quad * 8];
        half8 a1 = *(const half8*)&Asm[wm + 16 + l16][quad * 8];
        half8 b0 = *(const half8*)&Bsm[wn + l16][quad * 8];
        half8 b1 = *(const half8*)&Bsm[wn + 16 + l16][quad * 8];
        acc00 = __builtin_amdgcn_mfma_f32_16x16x32_f16(a0, b0, acc00, 0, 0, 0);
        acc01 = __builtin_amdgcn_mfma_f32_16x16x32_f16(a0, b1, acc01, 0, 0, 0);
        acc10 = __builtin_amdgcn_mfma_f32_16x16x32_f16(a1, b0, acc10, 0, 0, 0);
        acc11 = __builtin_amdgcn_mfma_f32_16x16x32_f16(a1, b1, acc11, 0, 0, 0);
    }
    // C/D layout: col = lane&15, row = (lane>>4)*4 + reg
    for (int r = 0; r < 4; r++) {
        int row0 = m0 + wm + quad * 4 + r;
        int row1 = row0 + 16;
        int col0 = n0 + wn + l16;
        C[(size_t)row0 * N + col0]      = acc00[r];
        C[(size_t)row0 * N + col0 + 16] = acc01[r];
        C[(size_t)row1 * N + col0]      = acc10[r];
        C[(size_t)row1 * N + col0 + 16] = acc11[r];
    }
}

// ---------------- RMSNorm + RoPE + reorder ----------------
// qkv [T][5120] fp32 -> Qf16 [NH][T][HD], Kf16 [NKV][T][HD], Vt [NKV][HD][T]
__global__ __launch_bounds__(256)
void qkv_post(const float* __restrict__ qkv, const int* __restrict__ positions,
              const float* __restrict__ qw, const float* __restrict__ kw,
              _Float16* __restrict__ Qb, _Float16* __restrict__ Kb,
              _Float16* __restrict__ Vt) {
    int t = blockIdx.x;
    int wave = threadIdx.x >> 6, lane = threadIdx.x & 63;
    float pos = (float)positions[t];
    // inv_freq for pair index d = lane: 1e6^(-lane/64) = 2^(-lane*log2(1e6)/64)
    float f = exp2f(-(float)lane * (19.9315685693241741f / 64.0f));
    float ang = pos * f;
    float s = sinf(ang), c = cosf(ang);
    const float* row = qkv + (size_t)t * QKV_DIM;
    for (int hh = wave; hh < NH + 2 * NKV; hh += 4) {
        float x1 = row[hh * HD + lane];
        float x2 = row[hh * HD + lane + 64];
        if (hh < NH + NKV) {
            float ss = x1 * x1 + x2 * x2;
            for (int o = 1; o < 64; o <<= 1) ss += __shfl_xor(ss, o);
            float inv = rsqrtf(ss * (1.0f / HD) + 1e-6f);
            const float* w = (hh < NH) ? qw : kw;
            x1 = x1 * inv * w[lane];
            x2 = x2 * inv * w[lane + 64];
            float y1 = x1 * c - x2 * s;
            float y2 = x2 * c + x1 * s;
            _Float16* dst;
            if (hh < NH) dst = Qb + ((size_t)hh * T + t) * HD;
            else         dst = Kb + ((size_t)(hh - NH) * T + t) * HD;
            dst[lane]      = (_Float16)y1;
            dst[lane + 64] = (_Float16)y2;
        } else {
            int hk = hh - NH - NKV;
            Vt[((size_t)hk * HD + lane) * T + t]      = (_Float16)x1;
            Vt[((size_t)hk * HD + lane + 64) * T + t] = (_Float16)x2;
        }
    }
}

// ---------------- Flash attention ----------------
// grid (qt=T/64, NH); 256 threads = 4 waves; wave w owns q rows [qt*64+w*16, +16)
__global__ __launch_bounds__(256)
void attn(const _Float16* __restrict__ Qb, const _Float16* __restrict__ Kb,
          const _Float16* __restrict__ Vt, _Float16* __restrict__ Ob) {
    __shared__ __align__(16) _Float16 Ksm[64][136];   // [kv][d], pad 136
    __shared__ __align__(16) _Float16 Vsm[128][72];   // [d][kv], pad 72
    __shared__ __align__(16) _Float16 Psm[4][16][72]; // per-wave P round-trip
    int qt = blockIdx.x, h = blockIdx.y;
    int hk = h >> 3;  // GQA: 8 q heads per kv head
    int tid = threadIdx.x, wave = tid >> 6, lane = tid & 63;
    int quad = lane >> 4, l16 = lane & 15;
    int q0 = qt * 64;
    int qrow = q0 + wave * 16 + l16;

    // Q fragments held in registers for the whole block
    half8 aq[4];
    for (int dk = 0; dk < 4; dk++)
        aq[dk] = *(const half8*)&Qb[((size_t)h * T + qrow) * HD + dk * 32 + quad * 8];

    floatx4 o_acc[8] = {};
    float m_i[4], l_i[4];
    for (int r = 0; r < 4; r++) { m_i[r] = -INFINITY; l_i[r] = 0.f; }
    int qrow_base = q0 + wave * 16 + quad * 4;

    int ntiles = qt + 1;
    for (int it = 0; it < ntiles; it++) {
        int kv0 = it * 64;
        __syncthreads();
        {   // stage K tile [64][128]
            int r = tid >> 4, cc = (tid & 15) * 8;
            for (int i = 0; i < 4; i++)
                *(half8*)&Ksm[r + i * 16][cc] =
                    *(const half8*)&Kb[((size_t)hk * T + kv0 + r + i * 16) * HD + cc];
            // stage V^T tile [128][64]
            int vr = tid >> 3, vc = (tid & 7) * 8;
            for (int i = 0; i < 4; i++)
                *(half8*)&Vsm[vr + i * 32][vc] =
                    *(const half8*)&Vt[((size_t)hk * HD + vr + i * 32) * T + kv0 + vc];
        }
        __syncthreads();

        // S = Q K^T : 4 kv sub-tiles of 16
        floatx4 sfr[4];
        for (int sn = 0; sn < 4; sn++) {
            floatx4 acc = {};
            for (int dk = 0; dk < 4; dk++) {
                half8 b = *(const half8*)&Ksm[sn * 16 + l16][dk * 32 + quad * 8];
                acc = __builtin_amdgcn_mfma_f32_16x16x32_f16(aq[dk], b, acc, 0, 0, 0);
            }
            sfr[sn] = acc;
        }
        // scale + causal mask + row max
        float tmax[4] = {-INFINITY, -INFINITY, -INFINITY, -INFINITY};
        for (int sn = 0; sn < 4; sn++) {
            int kv = kv0 + sn * 16 + l16;
            for (int r = 0; r < 4; r++) {
                float sv = sfr[sn][r] * SCALE;
                sv = (kv <= qrow_base + r) ? sv : -INFINITY;
                sfr[sn][r] = sv;
                tmax[r] = fmaxf(tmax[r], sv);
            }
        }
        for (int o = 1; o < 16; o <<= 1)
            for (int r = 0; r < 4; r++)
                tmax[r] = fmaxf(tmax[r], __shfl_xor(tmax[r], o));
        // online softmax update
        float alpha[4];
        for (int r = 0; r < 4; r++) {
            float mn = fmaxf(m_i[r], tmax[r]);
            alpha[r] = __expf(m_i[r] - mn);  // exp(-inf)=0: safe on tile 0
            m_i[r] = mn;
        }
        float tsum[4] = {0.f, 0.f, 0.f, 0.f};
        for (int sn = 0; sn < 4; sn++)
            for (int r = 0; r < 4; r++) {
                float p = __expf(sfr[sn][r] - m_i[r]);
                sfr[sn][r] = p;
                tsum[r] += p;
            }
        for (int o = 1; o < 16; o <<= 1)
            for (int r = 0; r < 4; r++) tsum[r] += __shfl_xor(tsum[r], o);
        for (int r = 0; r < 4; r++) l_i[r] = l_i[r] * alpha[r] + tsum[r];
        for (int dn = 0; dn < 8; dn++)
            for (int r = 0; r < 4; r++) o_acc[dn][r] *= alpha[r];

        // P: C-layout -> LDS -> A-layout
        for (int sn = 0; sn < 4; sn++)
            for (int r = 0; r < 4; r++)
                Psm[wave][quad * 4 + r][sn * 16 + l16] = (_Float16)sfr[sn][r];
        __syncthreads();  // conservative: ensure P visible before re-read
        half8 ap0 = *(const half8*)&Psm[wave][l16][quad * 8];
        half8 ap1 = *(const half8*)&Psm[wave][l16][32 + quad * 8];
        for (int dn = 0; dn < 8; dn++) {
            half8 bv0 = *(const half8*)&Vsm[dn * 16 + l16][quad * 8];
            half8 bv1 = *(const half8*)&Vsm[dn * 16 + l16][32 + quad * 8];
            o_acc[dn] = __builtin_amdgcn_mfma_f32_16x16x32_f16(ap0, bv0, o_acc[dn], 0, 0, 0);
            o_acc[dn] = __builtin_amdgcn_mfma_f32_16x16x32_f16(ap1, bv1, o_acc[dn], 0, 0, 0);
        }
    }
    // epilogue: 1/l, store fp16 to Ob [T][OD]
    float linv[4];
    for (int r = 0; r < 4; r++) linv[r] = 1.0f / l_i[r];
    for (int dn = 0; dn < 8; dn++)
        for (int r = 0; r < 4; r++) {
            int trow = q0 + wave * 16 + quad * 4 + r;
            int col = h * HD + dn * 16 + l16;
            Ob[(size_t)trow * OD + col] = (_Float16)(o_acc[dn][r] * linv[r]);
        }
}

extern "C" void kernel_launch(void* const* d_in, const int* in_sizes, int n_in,
                              void* d_out, int out_size, void* d_ws, size_t ws_size,
                              hipStream_t stream) {
    const int*   positions = (const int*)d_in[0];
    const float* hidden    = (const float*)d_in[1];
    const float* w_qkv     = (const float*)d_in[2];
    const float* w_o       = (const float*)d_in[3];
    const float* q_norm_w  = (const float*)d_in[4];
    const float* k_norm_w  = (const float*)d_in[5];
    float* out = (float*)d_out;

    char* ws = (char*)d_ws;
    _Float16* hb    = (_Float16*)(ws);                      // T*HID          (8 MiB)
    _Float16* wqkvb = (_Float16*)(ws + 8388608);            // 5120*2048      (20 MiB)
    _Float16* wob   = (_Float16*)(ws + 29360128);           // 2048*4096      (16 MiB)
    float*    qkvf  = (float*)   (ws + 46137344);           // T*5120 fp32    (40 MiB)
    _Float16* Qb    = (_Float16*)(ws + 88080384);           // NH*T*HD        (16 MiB)
    _Float16* Kb    = (_Float16*)(ws + 104857600);          // NKV*T*HD       (2 MiB)
    _Float16* Vt    = (_Float16*)(ws + 106954752);          // NKV*HD*T       (2 MiB)
    _Float16* Ob    = (_Float16*)(ws + 109051904);          // T*OD           (16 MiB)
    // total 120 MiB

    cvt_f16<<<(T * HID / 4 + 255) / 256, 256, 0, stream>>>(hidden, hb, T * HID);
    cvt_f16<<<(QKV_DIM * HID / 4 + 255) / 256, 256, 0, stream>>>(w_qkv, wqkvb, QKV_DIM * HID);
    cvt_f16<<<(HID * OD / 4 + 255) / 256, 256, 0, stream>>>(w_o, wob, HID * OD);

    // qkv = hidden @ w_qkv^T : [T,5120]
    gemm_nt<<<dim3(QKV_DIM / 64, T / 64), 256, 0, stream>>>(hb, wqkvb, qkvf, T, QKV_DIM, HID);

    qkv_post<<<T, 256, 0, stream>>>(qkvf, positions, q_norm_w, k_norm_w, Qb, Kb, Vt);

    attn<<<dim3(T / 64, NH), 256, 0, stream>>>(Qb, Kb, Vt, Ob);

    // out = Ob @ w_o^T : [T,2048]
    gemm_nt<<<dim3(HID / 64, T / 64), 256, 0, stream>>>(Ob, wob, out, T, HID, OD);
}

// Round 2
// 430.306 us; speedup vs baseline: 1.2293x; 1.2293x over previous
//
#include <hip/hip_runtime.h>
#include <math.h>

#define T 2048
#define HID 2048
#define NH 32
#define NKV 4
#define HD 128
#define QKV_DIM 5120   // (NH + 2*NKV) * HD
#define OD 4096        // NH * HD
#define SCALE 0.08838834764831845f

typedef _Float16 half8 __attribute__((ext_vector_type(8)));
typedef _Float16 half4v __attribute__((ext_vector_type(4)));
typedef float floatx4 __attribute__((ext_vector_type(4)));

// async global->LDS, 16B per lane; LDS dest is wave-uniform base + lane*16
#define GLD16(gp, lp) __builtin_amdgcn_global_load_lds( \
    (const __attribute__((address_space(1))) void*)(gp), \
    (__attribute__((address_space(3))) void*)(lp), 16, 0, 0)

// ---------------- fp32 -> fp16 conversion ----------------
__global__ __launch_bounds__(256)
void cvt_f16(const float* __restrict__ in, _Float16* __restrict__ out, int n) {
    int i = (blockIdx.x * 256 + threadIdx.x) * 4;
    if (i < n) {
        float4 v = *(const float4*)(in + i);
        half4v o = { (_Float16)v.x, (_Float16)v.y, (_Float16)v.z, (_Float16)v.w };
        *(half4v*)(out + i) = o;
    }
}

// ---------------- GEMM (NT): C[M,N] fp32 = A[M,K] * B[N,K]^T ----------------
// m97 structure: 128x128 tile, BK=32, global_load_lds w16, unpadded LDS.
__global__ __launch_bounds__(256)
void gemm_nt(const _Float16* __restrict__ A, const _Float16* __restrict__ B,
             float* __restrict__ C, int M, int N, int K) {
    __shared__ __align__(16) _Float16 Asm[4096];  // [128][32]
    __shared__ __align__(16) _Float16 Bsm[4096];  // [128][32]
    int tid = threadIdx.x;
    int wave = tid >> 6, lane = tid & 63;
    int quad = lane >> 4, l16 = lane & 15;
    int m0 = blockIdx.y * 128, n0 = blockIdx.x * 128;
    int wm = (wave >> 1) * 64, wn = (wave & 1) * 64;
    // staging: thread t covers row (t>>2) (+64 for chunk 1), cols (t&3)*8..+7
    const _Float16* Ag = A + (size_t)(m0 + (tid >> 2)) * K + (tid & 3) * 8;
    const _Float16* Bg = B + (size_t)(n0 + (tid >> 2)) * K + (tid & 3) * 8;
    size_t row64 = (size_t)64 * K;
    _Float16* AsmW = Asm + wave * 512;
    _Float16* BsmW = Bsm + wave * 512;
    floatx4 acc[4][4] = {};
    for (int k0 = 0; k0 < K; k0 += 32) {
        __syncthreads();
        GLD16(Ag + k0, AsmW);
        GLD16(Ag + row64 + k0, AsmW + 2048);
        GLD16(Bg + k0, BsmW);
        GLD16(Bg + row64 + k0, BsmW + 2048);
        __syncthreads();
        half8 af[4], bf[4];
        #pragma unroll
        for (int i = 0; i < 4; i++)
            af[i] = *(const half8*)&Asm[(wm + i * 16 + l16) * 32 + quad * 8];
        #pragma unroll
        for (int j = 0; j < 4; j++)
            bf[j] = *(const half8*)&Bsm[(wn + j * 16 + l16) * 32 + quad * 8];
        #pragma unroll
        for (int i = 0; i < 4; i++)
            #pragma unroll
            for (int j = 0; j < 4; j++)
                acc[i][j] = __builtin_amdgcn_mfma_f32_16x16x32_f16(af[i], bf[j], acc[i][j], 0, 0, 0);
    }
    #pragma unroll
    for (int i = 0; i < 4; i++) {
        int row = m0 + wm + i * 16 + quad * 4;
        #pragma unroll
        for (int j = 0; j < 4; j++) {
            int col = n0 + wn + j * 16 + l16;
            #pragma unroll
            for (int r = 0; r < 4; r++)
                C[(size_t)(row + r) * N + col] = acc[i][j][r];
        }
    }
}

// ---------------- RMSNorm + RoPE + reorder ----------------
__global__ __launch_bounds__(256)
void qkv_post(const float* __restrict__ qkv, const int* __restrict__ positions,
              const float* __restrict__ qw, const float* __restrict__ kw,
              _Float16* __restrict__ Qb, _Float16* __restrict__ Kb,
              _Float16* __restrict__ Vt) {
    int t = blockIdx.x;
    int wave = threadIdx.x >> 6, lane = threadIdx.x & 63;
    float pos = (float)positions[t];
    float f = exp2f(-(float)lane * (19.9315685693241741f / 64.0f));
    float ang = pos * f;
    float s = sinf(ang), c = cosf(ang);
    const float* row = qkv + (size_t)t * QKV_DIM;
    for (int hh = wave; hh < NH + 2 * NKV; hh += 4) {
        float x1 = row[hh * HD + lane];
        float x2 = row[hh * HD + lane + 64];
        if (hh < NH + NKV) {
            float ss = x1 * x1 + x2 * x2;
            for (int o = 1; o < 64; o <<= 1) ss += __shfl_xor(ss, o);
            float inv = rsqrtf(ss * (1.0f / HD) + 1e-6f);
            const float* w = (hh < NH) ? qw : kw;
            x1 = x1 * inv * w[lane];
            x2 = x2 * inv * w[lane + 64];
            float y1 = x1 * c - x2 * s;
            float y2 = x2 * c + x1 * s;
            _Float16* dst;
            if (hh < NH) dst = Qb + ((size_t)hh * T + t) * HD;
            else         dst = Kb + ((size_t)(hh - NH) * T + t) * HD;
            dst[lane]      = (_Float16)y1;
            dst[lane + 64] = (_Float16)y2;
        } else {
            int hk = hh - NH - NKV;
            Vt[((size_t)hk * HD + lane) * T + t]      = (_Float16)x1;
            Vt[((size_t)hk * HD + lane + 64) * T + t] = (_Float16)x2;
        }
    }
}

// ---------------- Flash attention ----------------
// 128 q-rows/block, 4 waves x 32 rows (2 groups of 16); kv tile 64.
// K/V staged via global_load_lds with XOR-swizzled (bank-conflict-free) layout.
__global__ __launch_bounds__(256)
void attn(const _Float16* __restrict__ Qb, const _Float16* __restrict__ Kb,
          const _Float16* __restrict__ Vt, _Float16* __restrict__ Ob) {
    __shared__ __align__(16) _Float16 Ksm[8192];    // [64][128] col-block ^ (row&7)
    __shared__ __align__(16) _Float16 Vsm[8192];    // [128][64] col-block ^ (row&7)
    __shared__ __align__(16) _Float16 Psm[4][16][72];
    int bx = blockIdx.x;
    int h = bx & 31;
    int qt = 15 - (bx >> 5);        // heavy tiles dispatched first
    int hk = h >> 3;
    int tid = threadIdx.x, wave = tid >> 6, lane = tid & 63;
    int quad = lane >> 4, l16 = lane & 15;
    int q0 = qt * 128;
    int wbase = q0 + wave * 32;

    half8 aq[2][4];
    #pragma unroll
    for (int g = 0; g < 2; g++) {
        int qrow = wbase + g * 16 + l16;
        const _Float16* qp = Qb + ((size_t)h * T + qrow) * HD + quad * 8;
        #pragma unroll
        for (int dk = 0; dk < 4; dk++)
            aq[g][dk] = *(const half8*)(qp + dk * 32);
    }
    floatx4 o_acc[2][8] = {};
    float m_i[2][4], l_i[2][4];
    #pragma unroll
    for (int g = 0; g < 2; g++)
        #pragma unroll
        for (int r = 0; r < 4; r++) { m_i[g][r] = -INFINITY; l_i[g][r] = 0.f; }

    int krow = tid >> 4;
    const _Float16* Kg = Kb + ((size_t)hk * T + krow) * HD + ((tid & 15) ^ (krow & 7)) * 8;
    int vrow = tid >> 3;
    const _Float16* Vg = Vt + ((size_t)hk * HD + vrow) * T + ((tid & 7) ^ (vrow & 7)) * 8;
    _Float16* KsmW = Ksm + wave * 512;
    _Float16* VsmW = Vsm + wave * 512;

    int ntiles = 2 * qt + 2;
    for (int it = 0; it < ntiles; it++) {
        int kv0 = it * 64;
        __syncthreads();
        {
            const _Float16* kg = Kg + (size_t)kv0 * HD;
            const _Float16* vg = Vg + kv0;
            #pragma unroll
            for (int c = 0; c < 4; c++) {
                GLD16(kg + (size_t)c * (16 * HD), KsmW + c * 2048);
                GLD16(vg + (size_t)c * (32 * T), VsmW + c * 2048);
            }
        }
        __syncthreads();
        if (kv0 > wbase + 31) continue;   // fully masked for this wave (barrier counts stay equal)

        // S = Q K^T  (K frags shared across both row-groups)
        floatx4 sfr[2][4];
        #pragma unroll
        for (int sn = 0; sn < 4; sn++) {
            int row = sn * 16 + l16;
            int rs = row & 7;
            half8 kf[4];
            #pragma unroll
            for (int dk = 0; dk < 4; dk++)
                kf[dk] = *(const half8*)&Ksm[row * 128 + ((dk * 4 + quad) ^ rs) * 8];
            #pragma unroll
            for (int g = 0; g < 2; g++) {
                floatx4 a = {};
                #pragma unroll
                for (int dk = 0; dk < 4; dk++)
                    a = __builtin_amdgcn_mfma_f32_16x16x32_f16(aq[g][dk], kf[dk], a, 0, 0, 0);
                sfr[g][sn] = a;
            }
        }

        bool act[2];
        half8 ap[2][2];
        #pragma unroll
        for (int g = 0; g < 2; g++) {
            int bg = wbase + g * 16;
            act[g] = (kv0 <= bg + 15);
            if (!act[g]) continue;
            bool needmask = (kv0 + 63 > bg);
            int rq = bg + quad * 4;
            float tmax[4] = {-INFINITY, -INFINITY, -INFINITY, -INFINITY};
            #pragma unroll
            for (int sn = 0; sn < 4; sn++) {
                int kv = kv0 + sn * 16 + l16;
                #pragma unroll
                for (int r = 0; r < 4; r++) {
                    float sv = sfr[g][sn][r] * SCALE;
                    if (needmask) sv = (kv <= rq + r) ? sv : -INFINITY;
                    sfr[g][sn][r] = sv;
                    tmax[r] = fmaxf(tmax[r], sv);
                }
            }
            #pragma unroll
            for (int o = 1; o < 16; o <<= 1)
                #pragma unroll
                for (int r = 0; r < 4; r++)
                    tmax[r] = fmaxf(tmax[r], __shfl_xor(tmax[r], o));
            float alpha[4];
            #pragma unroll
            for (int r = 0; r < 4; r++) {
                float mn = fmaxf(m_i[g][r], tmax[r]);
                alpha[r] = __expf(m_i[g][r] - mn);
                m_i[g][r] = mn;
            }
            float tsum[4] = {0.f, 0.f, 0.f, 0.f};
            #pragma unroll
            for (int sn = 0; sn < 4; sn++)
                #pragma unroll
                for (int r = 0; r < 4; r++) {
                    float p = __expf(sfr[g][sn][r] - m_i[g][r]);
                    tsum[r] += p;
                    Psm[wave][quad * 4 + r][sn * 16 + l16] = (_Float16)p;
                }
            #pragma unroll
            for (int o = 1; o < 16; o <<= 1)
                #pragma unroll
                for (int r = 0; r < 4; r++)
                    tsum[r] += __shfl_xor(tsum[r], o);
            #pragma unroll
            for (int r = 0; r < 4; r++)
                l_i[g][r] = l_i[g][r] * alpha[r] + tsum[r];
            #pragma unroll
            for (int dn = 0; dn < 8; dn++)
                #pragma unroll
                for (int r = 0; r < 4; r++)
                    o_acc[g][dn][r] *= alpha[r];
            // P: C-layout -> LDS -> A-layout (same-wave DS ops are in-order; no barrier)
            ap[g][0] = *(const half8*)&Psm[wave][l16][quad * 8];
            ap[g][1] = *(const half8*)&Psm[wave][l16][32 + quad * 8];
        }

        // PV (V frags shared across both row-groups)
        #pragma unroll
        for (int dn = 0; dn < 8; dn++) {
            int row = dn * 16 + l16;
            int rs = row & 7;
            half8 v0 = *(const half8*)&Vsm[row * 64 + ((quad ^ rs) * 8)];
            half8 v1 = *(const half8*)&Vsm[row * 64 + (((4 + quad) ^ rs) * 8)];
            #pragma unroll
            for (int g = 0; g < 2; g++) {
                if (!act[g]) continue;
                o_acc[g][dn] = __builtin_amdgcn_mfma_f32_16x16x32_f16(ap[g][0], v0, o_acc[g][dn], 0, 0, 0);
                o_acc[g][dn] = __builtin_amdgcn_mfma_f32_16x16x32_f16(ap[g][1], v1, o_acc[g][dn], 0, 0, 0);
            }
        }
    }

    #pragma unroll
    for (int g = 0; g < 2; g++) {
        float linv[4];
        #pragma unroll
        for (int r = 0; r < 4; r++) linv[r] = 1.0f / l_i[g][r];
        int rowb = wbase + g * 16 + quad * 4;
        #pragma unroll
        for (int dn = 0; dn < 8; dn++) {
            int col = h * HD + dn * 16 + l16;
            #pragma unroll
            for (int r = 0; r < 4; r++)
                Ob[(size_t)(rowb + r) * OD + col] = (_Float16)(o_acc[g][dn][r] * linv[r]);
        }
    }
}

extern "C" void kernel_launch(void* const* d_in, const int* in_sizes, int n_in,
                              void* d_out, int out_size, void* d_ws, size_t ws_size,
                              hipStream_t stream) {
    const int*   positions = (const int*)d_in[0];
    const float* hidden    = (const float*)d_in[1];
    const float* w_qkv     = (const float*)d_in[2];
    const float* w_o       = (const float*)d_in[3];
    const float* q_norm_w  = (const float*)d_in[4];
    const float* k_norm_w  = (const float*)d_in[5];
    float* out = (float*)d_out;

    char* ws = (char*)d_ws;
    _Float16* hb    = (_Float16*)(ws);                      // T*HID          (8 MiB)
    _Float16* wqkvb = (_Float16*)(ws + 8388608);            // 5120*2048      (20 MiB)
    _Float16* wob   = (_Float16*)(ws + 29360128);           // 2048*4096      (16 MiB)
    float*    qkvf  = (float*)   (ws + 46137344);           // T*5120 fp32    (40 MiB)
    _Float16* Qb    = (_Float16*)(ws + 88080384);           // NH*T*HD        (16 MiB)
    _Float16* Kb    = (_Float16*)(ws + 104857600);          // NKV*T*HD       (2 MiB)
    _Float16* Vt    = (_Float16*)(ws + 106954752);          // NKV*HD*T       (2 MiB)
    _Float16* Ob    = (_Float16*)(ws + 109051904);          // T*OD           (16 MiB)

    cvt_f16<<<(T * HID / 4 + 255) / 256, 256, 0, stream>>>(hidden, hb, T * HID);
    cvt_f16<<<(QKV_DIM * HID / 4 + 255) / 256, 256, 0, stream>>>(w_qkv, wqkvb, QKV_DIM * HID);
    cvt_f16<<<(HID * OD / 4 + 255) / 256, 256, 0, stream>>>(w_o, wob, HID * OD);

    gemm_nt<<<dim3(QKV_DIM / 128, T / 128), 256, 0, stream>>>(hb, wqkvb, qkvf, T, QKV_DIM, HID);

    qkv_post<<<T, 256, 0, stream>>>(qkvf, positions, q_norm_w, k_norm_w, Qb, Kb, Vt);

    attn<<<512, 256, 0, stream>>>(Qb, Kb, Vt, Ob);

    gemm_nt<<<dim3(HID / 128, T / 128), 256, 0, stream>>>(Ob, wob, out, T, HID, OD);
}

// Round 3
// 379.461 us; speedup vs baseline: 1.3940x; 1.1340x over previous
//
#include <hip/hip_runtime.h>
#include <math.h>

#define T 2048
#define HID 2048
#define NH 32
#define NKV 4
#define HD 128
#define QKV_DIM 5120   // (NH + 2*NKV) * HD
#define OD 4096        // NH * HD
// SCALE * log2(e): scores go straight to log2 domain
#define C2LOG 0.12751743f
#define MFIX 6.0f      // fixed softmax exponent shift (cancels in O/l)

typedef _Float16 half8 __attribute__((ext_vector_type(8)));
typedef _Float16 half4v __attribute__((ext_vector_type(4)));
typedef float floatx4 __attribute__((ext_vector_type(4)));

// async global->LDS, 16B per lane; LDS dest is wave-uniform base + lane*16
#define GLD16(gp, lp) __builtin_amdgcn_global_load_lds( \
    (const __attribute__((address_space(1))) void*)(gp), \
    (__attribute__((address_space(3))) void*)(lp), 16, 0, 0)

// ---------------- fp32 -> fp16 conversion ----------------
__global__ __launch_bounds__(256)
void cvt_f16(const float* __restrict__ in, _Float16* __restrict__ out, int n) {
    int i = (blockIdx.x * 256 + threadIdx.x) * 4;
    if (i < n) {
        float4 v = *(const float4*)(in + i);
        half4v o = { (_Float16)v.x, (_Float16)v.y, (_Float16)v.z, (_Float16)v.w };
        *(half4v*)(out + i) = o;
    }
}

__global__ void init_cnt(unsigned* c) { if (threadIdx.x == 0) *c = 0u; }

// ---------------- GEMM (NT) 128x128: C[M,N] fp32 = A[M,K] * B[N,K]^T -------
__global__ __launch_bounds__(256)
void gemm_nt(const _Float16* __restrict__ A, const _Float16* __restrict__ B,
             float* __restrict__ C, int M, int N, int K) {
    __shared__ __align__(16) _Float16 Asm[4096];  // [128][32]
    __shared__ __align__(16) _Float16 Bsm[4096];  // [128][32]
    int tid = threadIdx.x;
    int wave = tid >> 6, lane = tid & 63;
    int quad = lane >> 4, l16 = lane & 15;
    int m0 = blockIdx.y * 128, n0 = blockIdx.x * 128;
    int wm = (wave >> 1) * 64, wn = (wave & 1) * 64;
    const _Float16* Ag = A + (size_t)(m0 + (tid >> 2)) * K + (tid & 3) * 8;
    const _Float16* Bg = B + (size_t)(n0 + (tid >> 2)) * K + (tid & 3) * 8;
    size_t row64 = (size_t)64 * K;
    _Float16* AsmW = Asm + wave * 512;
    _Float16* BsmW = Bsm + wave * 512;
    floatx4 acc[4][4] = {};
    for (int k0 = 0; k0 < K; k0 += 32) {
        __syncthreads();
        GLD16(Ag + k0, AsmW);
        GLD16(Ag + row64 + k0, AsmW + 2048);
        GLD16(Bg + k0, BsmW);
        GLD16(Bg + row64 + k0, BsmW + 2048);
        __syncthreads();
        half8 af[4], bf[4];
        #pragma unroll
        for (int i = 0; i < 4; i++)
            af[i] = *(const half8*)&Asm[(wm + i * 16 + l16) * 32 + quad * 8];
        #pragma unroll
        for (int j = 0; j < 4; j++)
            bf[j] = *(const half8*)&Bsm[(wn + j * 16 + l16) * 32 + quad * 8];
        #pragma unroll
        for (int i = 0; i < 4; i++)
            #pragma unroll
            for (int j = 0; j < 4; j++)
                acc[i][j] = __builtin_amdgcn_mfma_f32_16x16x32_f16(af[i], bf[j], acc[i][j], 0, 0, 0);
    }
    #pragma unroll
    for (int i = 0; i < 4; i++) {
        int row = m0 + wm + i * 16 + quad * 4;
        #pragma unroll
        for (int j = 0; j < 4; j++) {
            int col = n0 + wn + j * 16 + l16;
            #pragma unroll
            for (int r = 0; r < 4; r++)
                C[(size_t)(row + r) * N + col] = acc[i][j][r];
        }
    }
}

// ---------------- GEMM (NT) 128x64: more blocks for small N ----------------
__global__ __launch_bounds__(256)
void gemm_nt_64(const _Float16* __restrict__ A, const _Float16* __restrict__ B,
                float* __restrict__ C, int M, int N, int K) {
    __shared__ __align__(16) _Float16 Asm[4096];  // [128][32]
    __shared__ __align__(16) _Float16 Bsm[2048];  // [64][32]
    int tid = threadIdx.x;
    int wave = tid >> 6, lane = tid & 63;
    int quad = lane >> 4, l16 = lane & 15;
    int m0 = blockIdx.y * 128, n0 = blockIdx.x * 64;
    int wm = wave * 32;
    const _Float16* Ag = A + (size_t)(m0 + (tid >> 2)) * K + (tid & 3) * 8;
    const _Float16* Bg = B + (size_t)(n0 + (tid >> 2)) * K + (tid & 3) * 8;
    size_t row64 = (size_t)64 * K;
    _Float16* AsmW = Asm + wave * 512;
    _Float16* BsmW = Bsm + wave * 512;
    floatx4 acc[2][4] = {};
    for (int k0 = 0; k0 < K; k0 += 32) {
        __syncthreads();
        GLD16(Ag + k0, AsmW);
        GLD16(Ag + row64 + k0, AsmW + 2048);
        GLD16(Bg + k0, BsmW);
        __syncthreads();
        half8 af[2], bf[4];
        #pragma unroll
        for (int i = 0; i < 2; i++)
            af[i] = *(const half8*)&Asm[(wm + i * 16 + l16) * 32 + quad * 8];
        #pragma unroll
        for (int j = 0; j < 4; j++)
            bf[j] = *(const half8*)&Bsm[(j * 16 + l16) * 32 + quad * 8];
        #pragma unroll
        for (int i = 0; i < 2; i++)
            #pragma unroll
            for (int j = 0; j < 4; j++)
                acc[i][j] = __builtin_amdgcn_mfma_f32_16x16x32_f16(af[i], bf[j], acc[i][j], 0, 0, 0);
    }
    #pragma unroll
    for (int i = 0; i < 2; i++) {
        int row = m0 + wm + i * 16 + quad * 4;
        #pragma unroll
        for (int j = 0; j < 4; j++) {
            int col = n0 + j * 16 + l16;
            #pragma unroll
            for (int r = 0; r < 4; r++)
                C[(size_t)(row + r) * N + col] = acc[i][j][r];
        }
    }
}

// ---------------- RMSNorm + RoPE + reorder ----------------
__global__ __launch_bounds__(256)
void qkv_post(const float* __restrict__ qkv, const int* __restrict__ positions,
              const float* __restrict__ qw, const float* __restrict__ kw,
              _Float16* __restrict__ Qb, _Float16* __restrict__ Kb,
              _Float16* __restrict__ Vt) {
    int t = blockIdx.x;
    int wave = threadIdx.x >> 6, lane = threadIdx.x & 63;
    float pos = (float)positions[t];
    float f = exp2f(-(float)lane * (19.9315685693241741f / 64.0f));
    float ang = pos * f;
    float s = sinf(ang), c = cosf(ang);
    const float* row = qkv + (size_t)t * QKV_DIM;
    for (int hh = wave; hh < NH + 2 * NKV; hh += 4) {
        float x1 = row[hh * HD + lane];
        float x2 = row[hh * HD + lane + 64];
        if (hh < NH + NKV) {
            float ss = x1 * x1 + x2 * x2;
            for (int o = 1; o < 64; o <<= 1) ss += __shfl_xor(ss, o);
            float inv = rsqrtf(ss * (1.0f / HD) + 1e-6f);
            const float* w = (hh < NH) ? qw : kw;
            x1 = x1 * inv * w[lane];
            x2 = x2 * inv * w[lane + 64];
            float y1 = x1 * c - x2 * s;
            float y2 = x2 * c + x1 * s;
            _Float16* dst;
            if (hh < NH) dst = Qb + ((size_t)hh * T + t) * HD;
            else         dst = Kb + ((size_t)(hh - NH) * T + t) * HD;
            dst[lane]      = (_Float16)y1;
            dst[lane + 64] = (_Float16)y2;
        } else {
            int hk = hh - NH - NKV;
            Vt[((size_t)hk * HD + lane) * T + t]      = (_Float16)x1;
            Vt[((size_t)hk * HD + lane + 64) * T + t] = (_Float16)x2;
        }
    }
}

// ---------------- Flash attention: persistent blocks + work queue ----------
// 512 items = (head, qt), heavy-first (LPT). 128 q-rows/item, kv tile 64.
// Fixed-exponent log2-domain softmax: P = 2^(s*C2LOG - MFIX); M cancels in O/l.
__global__ __launch_bounds__(256)
void attn(const _Float16* __restrict__ Qb, const _Float16* __restrict__ Kb,
          const _Float16* __restrict__ Vt, _Float16* __restrict__ Ob,
          unsigned* __restrict__ cnt) {
    __shared__ __align__(16) _Float16 Ksm[8192];    // [64][128] col-block ^ (row&7)
    __shared__ __align__(16) _Float16 Vsm[8192];    // [128][64] col-block ^ (row&7)
    __shared__ __align__(16) _Float16 Psm[4][16][72];
    __shared__ unsigned item_s;
    int tid = threadIdx.x, wave = tid >> 6, lane = tid & 63;
    int quad = lane >> 4, l16 = lane & 15;

    for (;;) {
        if (tid == 0) item_s = atomicAdd(cnt, 1u);
        __syncthreads();
        unsigned item = item_s;
        if (item >= 512u) break;
        int h = (int)(item & 31u);
        int qt = 15 - (int)(item >> 5);
        int hk = h >> 3;
        int q0 = qt * 128;
        int wbase = q0 + wave * 32;

        half8 aq[2][4];
        #pragma unroll
        for (int g = 0; g < 2; g++) {
            int qrow = wbase + g * 16 + l16;
            const _Float16* qp = Qb + ((size_t)h * T + qrow) * HD + quad * 8;
            #pragma unroll
            for (int dk = 0; dk < 4; dk++)
                aq[g][dk] = *(const half8*)(qp + dk * 32);
        }
        floatx4 o_acc[2][8] = {};
        float lpart[2][4] = {};

        int krow = tid >> 4;
        const _Float16* Kg = Kb + ((size_t)hk * T + krow) * HD + ((tid & 15) ^ (krow & 7)) * 8;
        int vrow = tid >> 3;
        const _Float16* Vg = Vt + ((size_t)hk * HD + vrow) * T + ((tid & 7) ^ (vrow & 7)) * 8;
        _Float16* KsmW = Ksm + wave * 512;
        _Float16* VsmW = Vsm + wave * 512;

        int ntiles = 2 * qt + 2;
        for (int it = 0; it < ntiles; it++) {
            int kv0 = it * 64;
            __syncthreads();
            {
                const _Float16* kg = Kg + (size_t)kv0 * HD;
                const _Float16* vg = Vg + kv0;
                #pragma unroll
                for (int c = 0; c < 4; c++) {
                    GLD16(kg + (size_t)c * (16 * HD), KsmW + c * 2048);
                    GLD16(vg + (size_t)c * (32 * T), VsmW + c * 2048);
                }
            }
            __syncthreads();
            if (kv0 > wbase + 31) continue;   // fully masked for this wave

            // S = Q K^T  (K frags shared across both row-groups)
            floatx4 sfr[2][4];
            #pragma unroll
            for (int sn = 0; sn < 4; sn++) {
                int row = sn * 16 + l16;
                int rs = row & 7;
                half8 kf[4];
                #pragma unroll
                for (int dk = 0; dk < 4; dk++)
                    kf[dk] = *(const half8*)&Ksm[row * 128 + ((dk * 4 + quad) ^ rs) * 8];
                #pragma unroll
                for (int g = 0; g < 2; g++) {
                    floatx4 a = {};
                    #pragma unroll
                    for (int dk = 0; dk < 4; dk++)
                        a = __builtin_amdgcn_mfma_f32_16x16x32_f16(aq[g][dk], kf[dk], a, 0, 0, 0);
                    sfr[g][sn] = a;
                }
            }

            bool act[2];
            half8 ap[2][2];
            #pragma unroll
            for (int g = 0; g < 2; g++) {
                int bg = wbase + g * 16;
                act[g] = (kv0 <= bg + 15);
                if (!act[g]) continue;
                bool needmask = (kv0 + 63 > bg);
                int rq = bg + quad * 4;
                #pragma unroll
                for (int sn = 0; sn < 4; sn++) {
                    int kv = kv0 + sn * 16 + l16;
                    #pragma unroll
                    for (int r = 0; r < 4; r++) {
                        float p = __builtin_amdgcn_exp2f(
                            __builtin_fmaf(sfr[g][sn][r], C2LOG, -MFIX));
                        if (needmask) p = (kv <= rq + r) ? p : 0.0f;
                        lpart[g][r] += p;
                        Psm[wave][quad * 4 + r][sn * 16 + l16] = (_Float16)p;
                    }
                }
                // same-wave DS ops are in-order; no barrier needed
                ap[g][0] = *(const half8*)&Psm[wave][l16][quad * 8];
                ap[g][1] = *(const half8*)&Psm[wave][l16][32 + quad * 8];
            }

            // PV (V frags shared across both row-groups)
            #pragma unroll
            for (int dn = 0; dn < 8; dn++) {
                int row = dn * 16 + l16;
                int rs = row & 7;
                half8 v0 = *(const half8*)&Vsm[row * 64 + ((quad ^ rs) * 8)];
                half8 v1 = *(const half8*)&Vsm[row * 64 + (((4 + quad) ^ rs) * 8)];
                #pragma unroll
                for (int g = 0; g < 2; g++) {
                    if (!act[g]) continue;
                    o_acc[g][dn] = __builtin_amdgcn_mfma_f32_16x16x32_f16(ap[g][0], v0, o_acc[g][dn], 0, 0, 0);
                    o_acc[g][dn] = __builtin_amdgcn_mfma_f32_16x16x32_f16(ap[g][1], v1, o_acc[g][dn], 0, 0, 0);
                }
            }
        }

        // one-time l reduction over the 16 column-lanes, then epilogue
        #pragma unroll
        for (int g = 0; g < 2; g++) {
            #pragma unroll
            for (int o = 1; o < 16; o <<= 1)
                #pragma unroll
                for (int r = 0; r < 4; r++)
                    lpart[g][r] += __shfl_xor(lpart[g][r], o);
            float linv[4];
            #pragma unroll
            for (int r = 0; r < 4; r++) linv[r] = 1.0f / lpart[g][r];
            int rowb = wbase + g * 16 + quad * 4;
            #pragma unroll
            for (int dn = 0; dn < 8; dn++) {
                int col = h * HD + dn * 16 + l16;
                #pragma unroll
                for (int r = 0; r < 4; r++)
                    Ob[(size_t)(rowb + r) * OD + col] = (_Float16)(o_acc[g][dn][r] * linv[r]);
            }
        }
    }
}

extern "C" void kernel_launch(void* const* d_in, const int* in_sizes, int n_in,
                              void* d_out, int out_size, void* d_ws, size_t ws_size,
                              hipStream_t stream) {
    const int*   positions = (const int*)d_in[0];
    const float* hidden    = (const float*)d_in[1];
    const float* w_qkv     = (const float*)d_in[2];
    const float* w_o       = (const float*)d_in[3];
    const float* q_norm_w  = (const float*)d_in[4];
    const float* k_norm_w  = (const float*)d_in[5];
    float* out = (float*)d_out;

    char* ws = (char*)d_ws;
    _Float16* hb    = (_Float16*)(ws);                      // T*HID          (8 MiB)
    _Float16* wqkvb = (_Float16*)(ws + 8388608);            // 5120*2048      (20 MiB)
    _Float16* wob   = (_Float16*)(ws + 29360128);           // 2048*4096      (16 MiB)
    float*    qkvf  = (float*)   (ws + 46137344);           // T*5120 fp32    (40 MiB)
    _Float16* Qb    = (_Float16*)(ws + 88080384);           // NH*T*HD        (16 MiB)
    _Float16* Kb    = (_Float16*)(ws + 104857600);          // NKV*T*HD       (2 MiB)
    _Float16* Vt    = (_Float16*)(ws + 106954752);          // NKV*HD*T       (2 MiB)
    _Float16* Ob    = (_Float16*)(ws + 109051904);          // T*OD           (16 MiB)
    unsigned* cnt   = (unsigned*)(ws + 125829120);          // work-queue counter

    cvt_f16<<<(T * HID / 4 + 255) / 256, 256, 0, stream>>>(hidden, hb, T * HID);
    cvt_f16<<<(QKV_DIM * HID / 4 + 255) / 256, 256, 0, stream>>>(w_qkv, wqkvb, QKV_DIM * HID);
    cvt_f16<<<(HID * OD / 4 + 255) / 256, 256, 0, stream>>>(w_o, wob, HID * OD);

    gemm_nt<<<dim3(QKV_DIM / 128, T / 128), 256, 0, stream>>>(hb, wqkvb, qkvf, T, QKV_DIM, HID);

    qkv_post<<<T, 256, 0, stream>>>(qkvf, positions, q_norm_w, k_norm_w, Qb, Kb, Vt);

    init_cnt<<<1, 64, 0, stream>>>(cnt);
    attn<<<768, 256, 0, stream>>>(Qb, Kb, Vt, Ob, cnt);

    gemm_nt_64<<<dim3(HID / 64, T / 128), 256, 0, stream>>>(Ob, wob, out, T, HID, OD);
}

// Round 4
// 350.035 us; speedup vs baseline: 1.5112x; 1.0841x over previous
//
#include <hip/hip_runtime.h>
#include <math.h>

#define T 2048
#define HID 2048
#define NH 32
#define NKV 4
#define HD 128
#define QKV_DIM 5120   // (NH + 2*NKV) * HD
#define OD 4096        // NH * HD
// SCALE * log2(e): scores go straight to log2 domain
#define C2LOG 0.12751743f
#define MFIX 6.0f      // fixed softmax exponent shift (cancels in O/l)

typedef _Float16 half8 __attribute__((ext_vector_type(8)));
typedef _Float16 half4v __attribute__((ext_vector_type(4)));
typedef float floatx4 __attribute__((ext_vector_type(4)));

// async global->LDS, 16B per lane; LDS dest is wave-uniform base + lane*16
#define GLD16(gp, lp) __builtin_amdgcn_global_load_lds( \
    (const __attribute__((address_space(1))) void*)(gp), \
    (__attribute__((address_space(3))) void*)(lp), 16, 0, 0)

// ---------------- fused fp32 -> fp16 conversion (hidden, w_qkv, w_o) -------
// dests are contiguous in ws starting at hb
__global__ __launch_bounds__(256)
void cvt_all(const float* __restrict__ h, const float* __restrict__ wq,
             const float* __restrict__ wo, _Float16* __restrict__ out) {
    size_t i = ((size_t)blockIdx.x * 256 + threadIdx.x) * 4;
    const float* src;
    size_t off;
    if (i < (size_t)T * HID)                        { src = h;  off = i; }
    else if (i < (size_t)T * HID + (size_t)QKV_DIM * HID)
                                                    { src = wq; off = i - (size_t)T * HID; }
    else                                            { src = wo; off = i - (size_t)T * HID - (size_t)QKV_DIM * HID; }
    float4 v = *(const float4*)(src + off);
    half4v o = { (_Float16)v.x, (_Float16)v.y, (_Float16)v.z, (_Float16)v.w };
    *(half4v*)(out + i) = o;
}

// ---------------- GEMM (NT) 128x128, fp16 output: C = A * B^T --------------
__global__ __launch_bounds__(256)
void gemm_nt_h(const _Float16* __restrict__ A, const _Float16* __restrict__ B,
               _Float16* __restrict__ C, int M, int N, int K) {
    __shared__ __align__(16) _Float16 Asm[4096];  // [128][32]
    __shared__ __align__(16) _Float16 Bsm[4096];  // [128][32]
    int tid = threadIdx.x;
    int wave = tid >> 6, lane = tid & 63;
    int quad = lane >> 4, l16 = lane & 15;
    int m0 = blockIdx.y * 128, n0 = blockIdx.x * 128;
    int wm = (wave >> 1) * 64, wn = (wave & 1) * 64;
    const _Float16* Ag = A + (size_t)(m0 + (tid >> 2)) * K + (tid & 3) * 8;
    const _Float16* Bg = B + (size_t)(n0 + (tid >> 2)) * K + (tid & 3) * 8;
    size_t row64 = (size_t)64 * K;
    _Float16* AsmW = Asm + wave * 512;
    _Float16* BsmW = Bsm + wave * 512;
    floatx4 acc[4][4] = {};
    for (int k0 = 0; k0 < K; k0 += 32) {
        __syncthreads();
        GLD16(Ag + k0, AsmW);
        GLD16(Ag + row64 + k0, AsmW + 2048);
        GLD16(Bg + k0, BsmW);
        GLD16(Bg + row64 + k0, BsmW + 2048);
        __syncthreads();
        half8 af[4], bf[4];
        #pragma unroll
        for (int i = 0; i < 4; i++)
            af[i] = *(const half8*)&Asm[(wm + i * 16 + l16) * 32 + quad * 8];
        #pragma unroll
        for (int j = 0; j < 4; j++)
            bf[j] = *(const half8*)&Bsm[(wn + j * 16 + l16) * 32 + quad * 8];
        #pragma unroll
        for (int i = 0; i < 4; i++)
            #pragma unroll
            for (int j = 0; j < 4; j++)
                acc[i][j] = __builtin_amdgcn_mfma_f32_16x16x32_f16(af[i], bf[j], acc[i][j], 0, 0, 0);
    }
    #pragma unroll
    for (int i = 0; i < 4; i++) {
        int row = m0 + wm + i * 16 + quad * 4;
        #pragma unroll
        for (int j = 0; j < 4; j++) {
            int col = n0 + wn + j * 16 + l16;
            #pragma unroll
            for (int r = 0; r < 4; r++)
                C[(size_t)(row + r) * N + col] = (_Float16)acc[i][j][r];
        }
    }
}

// ---------------- GEMM (NT) 128x64, fp32 output ----------------------------
__global__ __launch_bounds__(256)
void gemm_nt_64(const _Float16* __restrict__ A, const _Float16* __restrict__ B,
                float* __restrict__ C, int M, int N, int K) {
    __shared__ __align__(16) _Float16 Asm[4096];  // [128][32]
    __shared__ __align__(16) _Float16 Bsm[2048];  // [64][32]
    int tid = threadIdx.x;
    int wave = tid >> 6, lane = tid & 63;
    int quad = lane >> 4, l16 = lane & 15;
    int m0 = blockIdx.y * 128, n0 = blockIdx.x * 64;
    int wm = wave * 32;
    const _Float16* Ag = A + (size_t)(m0 + (tid >> 2)) * K + (tid & 3) * 8;
    const _Float16* Bg = B + (size_t)(n0 + (tid >> 2)) * K + (tid & 3) * 8;
    size_t row64 = (size_t)64 * K;
    _Float16* AsmW = Asm + wave * 512;
    _Float16* BsmW = Bsm + wave * 512;
    floatx4 acc[2][4] = {};
    for (int k0 = 0; k0 < K; k0 += 32) {
        __syncthreads();
        GLD16(Ag + k0, AsmW);
        GLD16(Ag + row64 + k0, AsmW + 2048);
        GLD16(Bg + k0, BsmW);
        __syncthreads();
        half8 af[2], bf[4];
        #pragma unroll
        for (int i = 0; i < 2; i++)
            af[i] = *(const half8*)&Asm[(wm + i * 16 + l16) * 32 + quad * 8];
        #pragma unroll
        for (int j = 0; j < 4; j++)
            bf[j] = *(const half8*)&Bsm[(j * 16 + l16) * 32 + quad * 8];
        #pragma unroll
        for (int i = 0; i < 2; i++)
            #pragma unroll
            for (int j = 0; j < 4; j++)
                acc[i][j] = __builtin_amdgcn_mfma_f32_16x16x32_f16(af[i], bf[j], acc[i][j], 0, 0, 0);
    }
    #pragma unroll
    for (int i = 0; i < 2; i++) {
        int row = m0 + wm + i * 16 + quad * 4;
        #pragma unroll
        for (int j = 0; j < 4; j++) {
            int col = n0 + j * 16 + l16;
            #pragma unroll
            for (int r = 0; r < 4; r++)
                C[(size_t)(row + r) * N + col] = acc[i][j][r];
        }
    }
}

// ---------------- RMSNorm + RoPE + reorder (fp16 in) -----------------------
__global__ __launch_bounds__(256)
void qkv_post(const _Float16* __restrict__ qkv, const int* __restrict__ positions,
              const float* __restrict__ qw, const float* __restrict__ kw,
              _Float16* __restrict__ Qb, _Float16* __restrict__ Kb,
              _Float16* __restrict__ Vt) {
    int t = blockIdx.x;
    int wave = threadIdx.x >> 6, lane = threadIdx.x & 63;
    float pos = (float)positions[t];
    float f = exp2f(-(float)lane * (19.9315685693241741f / 64.0f));
    float ang = pos * f;
    float s = sinf(ang), c = cosf(ang);
    const _Float16* row = qkv + (size_t)t * QKV_DIM;
    for (int hh = wave; hh < NH + 2 * NKV; hh += 4) {
        float x1 = (float)row[hh * HD + lane];
        float x2 = (float)row[hh * HD + lane + 64];
        if (hh < NH + NKV) {
            float ss = x1 * x1 + x2 * x2;
            for (int o = 1; o < 64; o <<= 1) ss += __shfl_xor(ss, o);
            float inv = rsqrtf(ss * (1.0f / HD) + 1e-6f);
            const float* w = (hh < NH) ? qw : kw;
            x1 = x1 * inv * w[lane];
            x2 = x2 * inv * w[lane + 64];
            float y1 = x1 * c - x2 * s;
            float y2 = x2 * c + x1 * s;
            _Float16* dst;
            if (hh < NH) dst = Qb + ((size_t)hh * T + t) * HD;
            else         dst = Kb + ((size_t)(hh - NH) * T + t) * HD;
            dst[lane]      = (_Float16)y1;
            dst[lane + 64] = (_Float16)y2;
        } else {
            int hk = hh - NH - NKV;
            Vt[((size_t)hk * HD + lane) * T + t]      = (_Float16)x1;
            Vt[((size_t)hk * HD + lane + 64) * T + t] = (_Float16)x2;
        }
    }
}

// ---------------- Flash attention: 1024 blocks x 64 q-rows -----------------
// Static balanced schedule: the 4 blocks sharing (b&255) carry qt sets
// {31-i, i, 23-i, 8+i} -> uniform 66 kv-tiles per CU under round-robin
// dispatch. LDS = 16K (K) + 16K (V) + 8K (P, XOR-swizzled) = 40960 B ->
// 4 blocks/CU resident. Fixed-exponent log2-domain softmax.
__global__ __launch_bounds__(256, 4)
void attn(const _Float16* __restrict__ Qb, const _Float16* __restrict__ Kb,
          const _Float16* __restrict__ Vt, _Float16* __restrict__ Ob) {
    __shared__ __align__(16) _Float16 Ksm[8192];    // [64][128] col-block ^ (row&7)
    __shared__ __align__(16) _Float16 Vsm[8192];    // [128][64] col-block ^ (row&7)
    __shared__ __align__(16) _Float16 Psm[4][1024]; // per-wave [16][64] swizzled
    int b = blockIdx.x;
    int h = b & 31;
    int quarter = b >> 8;
    int i = (b & 255) >> 5;
    int qt = (quarter == 0) ? 31 - i : (quarter == 1) ? i
           : (quarter == 2) ? 23 - i : 8 + i;
    int hk = h >> 3;
    int tid = threadIdx.x, wave = tid >> 6, lane = tid & 63;
    int quad = lane >> 4, l16 = lane & 15;
    int q0 = qt * 64;
    int wbase = q0 + wave * 16;

    // Q fragments: 16 rows/wave, held for the whole item
    half8 aq[4];
    {
        const _Float16* qp = Qb + ((size_t)h * T + wbase + l16) * HD + quad * 8;
        #pragma unroll
        for (int dk = 0; dk < 4; dk++)
            aq[dk] = *(const half8*)(qp + dk * 32);
    }
    floatx4 o_acc[8] = {};
    float lpart[4] = {};

    int krow = tid >> 4;
    const _Float16* Kg = Kb + ((size_t)hk * T + krow) * HD + ((tid & 15) ^ (krow & 7)) * 8;
    int vrow = tid >> 3;
    const _Float16* Vg = Vt + ((size_t)hk * HD + vrow) * T + ((tid & 7) ^ (vrow & 7)) * 8;
    _Float16* KsmW = Ksm + wave * 512;
    _Float16* VsmW = Vsm + wave * 512;
    _Float16* PsmW = Psm[wave];

    int ntiles = qt + 1;
    for (int it = 0; it < ntiles; it++) {
        int kv0 = it * 64;
        __syncthreads();
        {
            const _Float16* kg = Kg + (size_t)kv0 * HD;
            const _Float16* vg = Vg + kv0;
            #pragma unroll
            for (int c = 0; c < 4; c++) {
                GLD16(kg + (size_t)c * (16 * HD), KsmW + c * 2048);
                GLD16(vg + (size_t)c * (32 * T), VsmW + c * 2048);
            }
        }
        __syncthreads();

        // S = Q K^T
        floatx4 sfr[4];
        #pragma unroll
        for (int sn = 0; sn < 4; sn++) {
            int row = sn * 16 + l16;
            int rs = row & 7;
            floatx4 a = {};
            #pragma unroll
            for (int dk = 0; dk < 4; dk++) {
                half8 kf = *(const half8*)&Ksm[row * 128 + ((dk * 4 + quad) ^ rs) * 8];
                a = __builtin_amdgcn_mfma_f32_16x16x32_f16(aq[dk], kf, a, 0, 0, 0);
            }
            sfr[sn] = a;
        }

        // P = 2^(s*C2LOG - MFIX), causal mask on the diagonal tile only
        bool needmask = (it == ntiles - 1);
        int rq = wbase + quad * 4;
        #pragma unroll
        for (int sn = 0; sn < 4; sn++) {
            int kv = kv0 + sn * 16 + l16;
            #pragma unroll
            for (int r = 0; r < 4; r++) {
                float p = __builtin_amdgcn_exp2f(
                    __builtin_fmaf(sfr[sn][r], C2LOG, -MFIX));
                if (needmask) p = (kv <= rq + r) ? p : 0.0f;
                lpart[r] += p;
                int prow = quad * 4 + r;
                int cb = sn * 2 + (l16 >> 3);
                PsmW[prow * 64 + ((cb ^ (prow & 7)) * 8 + (l16 & 7))] = (_Float16)p;
            }
        }
        // same-wave DS ops are in-order; no barrier needed
        half8 ap0 = *(const half8*)&PsmW[l16 * 64 + ((quad ^ (l16 & 7)) * 8)];
        half8 ap1 = *(const half8*)&PsmW[l16 * 64 + (((4 + quad) ^ (l16 & 7)) * 8)];

        // O += P V
        #pragma unroll
        for (int dn = 0; dn < 8; dn++) {
            int row = dn * 16 + l16;
            int rs = row & 7;
            half8 v0 = *(const half8*)&Vsm[row * 64 + ((quad ^ rs) * 8)];
            half8 v1 = *(const half8*)&Vsm[row * 64 + (((4 + quad) ^ rs) * 8)];
            o_acc[dn] = __builtin_amdgcn_mfma_f32_16x16x32_f16(ap0, v0, o_acc[dn], 0, 0, 0);
            o_acc[dn] = __builtin_amdgcn_mfma_f32_16x16x32_f16(ap1, v1, o_acc[dn], 0, 0, 0);
        }
    }

    // l reduction over the 16 column-lanes, then epilogue
    #pragma unroll
    for (int o = 1; o < 16; o <<= 1)
        #pragma unroll
        for (int r = 0; r < 4; r++)
            lpart[r] += __shfl_xor(lpart[r], o);
    float linv[4];
    #pragma unroll
    for (int r = 0; r < 4; r++) linv[r] = 1.0f / lpart[r];
    int rowb = wbase + quad * 4;
    #pragma unroll
    for (int dn = 0; dn < 8; dn++) {
        int col = h * HD + dn * 16 + l16;
        #pragma unroll
        for (int r = 0; r < 4; r++)
            Ob[(size_t)(rowb + r) * OD + col] = (_Float16)(o_acc[dn][r] * linv[r]);
    }
}

extern "C" void kernel_launch(void* const* d_in, const int* in_sizes, int n_in,
                              void* d_out, int out_size, void* d_ws, size_t ws_size,
                              hipStream_t stream) {
    const int*   positions = (const int*)d_in[0];
    const float* hidden    = (const float*)d_in[1];
    const float* w_qkv     = (const float*)d_in[2];
    const float* w_o       = (const float*)d_in[3];
    const float* q_norm_w  = (const float*)d_in[4];
    const float* k_norm_w  = (const float*)d_in[5];
    float* out = (float*)d_out;

    char* ws = (char*)d_ws;
    _Float16* hb    = (_Float16*)(ws);                      // T*HID          (8 MiB)
    _Float16* wqkvb = (_Float16*)(ws + 8388608);            // 5120*2048      (20 MiB)
    _Float16* wob   = (_Float16*)(ws + 29360128);           // 2048*4096      (16 MiB)
    _Float16* qkvh  = (_Float16*)(ws + 46137344);           // T*5120 fp16    (20 MiB)
    _Float16* Qb    = (_Float16*)(ws + 88080384);           // NH*T*HD        (16 MiB)
    _Float16* Kb    = (_Float16*)(ws + 104857600);          // NKV*T*HD       (2 MiB)
    _Float16* Vt    = (_Float16*)(ws + 106954752);          // NKV*HD*T       (2 MiB)
    _Float16* Ob    = (_Float16*)(ws + 109051904);          // T*OD           (16 MiB)

    // fused conversions: dests contiguous starting at hb
    cvt_all<<<22528, 256, 0, stream>>>(hidden, w_qkv, w_o, hb);

    gemm_nt_h<<<dim3(QKV_DIM / 128, T / 128), 256, 0, stream>>>(hb, wqkvb, qkvh, T, QKV_DIM, HID);

    qkv_post<<<T, 256, 0, stream>>>(qkvh, positions, q_norm_w, k_norm_w, Qb, Kb, Vt);

    attn<<<1024, 256, 0, stream>>>(Qb, Kb, Vt, Ob);

    gemm_nt_64<<<dim3(HID / 64, T / 128), 256, 0, stream>>>(Ob, wob, out, T, HID, OD);
}

// Round 5
// 343.011 us; speedup vs baseline: 1.5421x; 1.0205x over previous
//
#include <hip/hip_runtime.h>
#include <math.h>

#define T 2048
#define HID 2048
#define NH 32
#define NKV 4
#define HD 128
#define QKV_DIM 5120   // (NH + 2*NKV) * HD
#define OD 4096        // NH * HD
// SCALE * log2(e): scores go straight to log2 domain
#define C2LOG 0.12751743f
#define MFIX 6.0f      // fixed softmax exponent shift (cancels in O/l)

typedef _Float16 half8 __attribute__((ext_vector_type(8)));
typedef _Float16 half4v __attribute__((ext_vector_type(4)));
typedef float floatx4 __attribute__((ext_vector_type(4)));

// async global->LDS, 16B per lane; LDS dest is wave-uniform base + lane*16
#define GLD16(gp, lp) __builtin_amdgcn_global_load_lds( \
    (const __attribute__((address_space(1))) void*)(gp), \
    (__attribute__((address_space(3))) void*)(lp), 16, 0, 0)

// ---------------- fused fp32 -> fp16 conversion (hidden, w_qkv, w_o) -------
__global__ __launch_bounds__(256)
void cvt_all(const float* __restrict__ h, const float* __restrict__ wq,
             const float* __restrict__ wo, _Float16* __restrict__ out) {
    size_t i = ((size_t)blockIdx.x * 256 + threadIdx.x) * 4;
    const float* src;
    size_t off;
    if (i < (size_t)T * HID)                        { src = h;  off = i; }
    else if (i < (size_t)T * HID + (size_t)QKV_DIM * HID)
                                                    { src = wq; off = i - (size_t)T * HID; }
    else                                            { src = wo; off = i - (size_t)T * HID - (size_t)QKV_DIM * HID; }
    float4 v = *(const float4*)(src + off);
    half4v o = { (_Float16)v.x, (_Float16)v.y, (_Float16)v.z, (_Float16)v.w };
    *(half4v*)(out + i) = o;
}

// -------- split-K GEMM (NT), fp16 partial out: P[z] = A * B^T over K-slice --
// m97 structure: 128x128 tile, BK=32, global_load_lds w16, unpadded LDS.
__global__ __launch_bounds__(256)
void gemm_sk_h(const _Float16* __restrict__ A, const _Float16* __restrict__ B,
               _Float16* __restrict__ p0, _Float16* __restrict__ p1,
               int M, int N, int K, int KS) {
    __shared__ __align__(16) _Float16 Asm[4096];  // [128][32]
    __shared__ __align__(16) _Float16 Bsm[4096];  // [128][32]
    int tid = threadIdx.x;
    int wave = tid >> 6, lane = tid & 63;
    int quad = lane >> 4, l16 = lane & 15;
    int m0 = blockIdx.y * 128, n0 = blockIdx.x * 128;
    int koff = blockIdx.z * KS;
    _Float16* C = blockIdx.z ? p1 : p0;
    int wm = (wave >> 1) * 64, wn = (wave & 1) * 64;
    const _Float16* Ag = A + (size_t)(m0 + (tid >> 2)) * K + koff + (tid & 3) * 8;
    const _Float16* Bg = B + (size_t)(n0 + (tid >> 2)) * K + koff + (tid & 3) * 8;
    size_t row64 = (size_t)64 * K;
    _Float16* AsmW = Asm + wave * 512;
    _Float16* BsmW = Bsm + wave * 512;
    floatx4 acc[4][4] = {};
    for (int k0 = 0; k0 < KS; k0 += 32) {
        __syncthreads();
        GLD16(Ag + k0, AsmW);
        GLD16(Ag + row64 + k0, AsmW + 2048);
        GLD16(Bg + k0, BsmW);
        GLD16(Bg + row64 + k0, BsmW + 2048);
        __syncthreads();
        half8 af[4], bf[4];
        #pragma unroll
        for (int i = 0; i < 4; i++)
            af[i] = *(const half8*)&Asm[(wm + i * 16 + l16) * 32 + quad * 8];
        #pragma unroll
        for (int j = 0; j < 4; j++)
            bf[j] = *(const half8*)&Bsm[(wn + j * 16 + l16) * 32 + quad * 8];
        #pragma unroll
        for (int i = 0; i < 4; i++)
            #pragma unroll
            for (int j = 0; j < 4; j++)
                acc[i][j] = __builtin_amdgcn_mfma_f32_16x16x32_f16(af[i], bf[j], acc[i][j], 0, 0, 0);
    }
    #pragma unroll
    for (int i = 0; i < 4; i++) {
        int row = m0 + wm + i * 16 + quad * 4;
        #pragma unroll
        for (int j = 0; j < 4; j++) {
            int col = n0 + wn + j * 16 + l16;
            #pragma unroll
            for (int r = 0; r < 4; r++)
                C[(size_t)(row + r) * N + col] = (_Float16)acc[i][j][r];
        }
    }
}

// -------- split-K GEMM (NT), fp32 partials x4 -------------------------------
__global__ __launch_bounds__(256)
void gemm_sk_f(const _Float16* __restrict__ A, const _Float16* __restrict__ B,
               float* __restrict__ p0, float* __restrict__ p1,
               float* __restrict__ p2, float* __restrict__ p3,
               int M, int N, int K, int KS) {
    __shared__ __align__(16) _Float16 Asm[4096];
    __shared__ __align__(16) _Float16 Bsm[4096];
    int tid = threadIdx.x;
    int wave = tid >> 6, lane = tid & 63;
    int quad = lane >> 4, l16 = lane & 15;
    int m0 = blockIdx.y * 128, n0 = blockIdx.x * 128;
    int bz = blockIdx.z;
    int koff = bz * KS;
    float* C = (bz == 0) ? p0 : (bz == 1) ? p1 : (bz == 2) ? p2 : p3;
    int wm = (wave >> 1) * 64, wn = (wave & 1) * 64;
    const _Float16* Ag = A + (size_t)(m0 + (tid >> 2)) * K + koff + (tid & 3) * 8;
    const _Float16* Bg = B + (size_t)(n0 + (tid >> 2)) * K + koff + (tid & 3) * 8;
    size_t row64 = (size_t)64 * K;
    _Float16* AsmW = Asm + wave * 512;
    _Float16* BsmW = Bsm + wave * 512;
    floatx4 acc[4][4] = {};
    for (int k0 = 0; k0 < KS; k0 += 32) {
        __syncthreads();
        GLD16(Ag + k0, AsmW);
        GLD16(Ag + row64 + k0, AsmW + 2048);
        GLD16(Bg + k0, BsmW);
        GLD16(Bg + row64 + k0, BsmW + 2048);
        __syncthreads();
        half8 af[4], bf[4];
        #pragma unroll
        for (int i = 0; i < 4; i++)
            af[i] = *(const half8*)&Asm[(wm + i * 16 + l16) * 32 + quad * 8];
        #pragma unroll
        for (int j = 0; j < 4; j++)
            bf[j] = *(const half8*)&Bsm[(wn + j * 16 + l16) * 32 + quad * 8];
        #pragma unroll
        for (int i = 0; i < 4; i++)
            #pragma unroll
            for (int j = 0; j < 4; j++)
                acc[i][j] = __builtin_amdgcn_mfma_f32_16x16x32_f16(af[i], bf[j], acc[i][j], 0, 0, 0);
    }
    #pragma unroll
    for (int i = 0; i < 4; i++) {
        int row = m0 + wm + i * 16 + quad * 4;
        #pragma unroll
        for (int j = 0; j < 4; j++) {
            int col = n0 + wn + j * 16 + l16;
            #pragma unroll
            for (int r = 0; r < 4; r++)
                C[(size_t)(row + r) * N + col] = acc[i][j][r];
        }
    }
}

// ---------------- reduce 4 fp32 partials -> fp32 out ------------------------
__global__ __launch_bounds__(256)
void reduce4(const float* __restrict__ p0, const float* __restrict__ p1,
             const float* __restrict__ p2, const float* __restrict__ p3,
             float* __restrict__ out) {
    size_t i = ((size_t)blockIdx.x * 256 + threadIdx.x) * 4;
    float4 a = *(const float4*)(p0 + i);
    float4 b = *(const float4*)(p1 + i);
    float4 c = *(const float4*)(p2 + i);
    float4 d = *(const float4*)(p3 + i);
    float4 o = { a.x + b.x + c.x + d.x, a.y + b.y + c.y + d.y,
                 a.z + b.z + c.z + d.z, a.w + b.w + c.w + d.w };
    *(float4*)(out + i) = o;
}

// ---------------- RMSNorm + RoPE + reorder (sums 2 fp16 partials) ----------
__global__ __launch_bounds__(256)
void qkv_post(const _Float16* __restrict__ qp0, const _Float16* __restrict__ qp1,
              const int* __restrict__ positions,
              const float* __restrict__ qw, const float* __restrict__ kw,
              _Float16* __restrict__ Qb, _Float16* __restrict__ Kb,
              _Float16* __restrict__ Vt) {
    int t = blockIdx.x;
    int wave = threadIdx.x >> 6, lane = threadIdx.x & 63;
    float pos = (float)positions[t];
    float f = exp2f(-(float)lane * (19.9315685693241741f / 64.0f));
    float ang = pos * f;
    float s = sinf(ang), c = cosf(ang);
    const _Float16* r0 = qp0 + (size_t)t * QKV_DIM;
    const _Float16* r1 = qp1 + (size_t)t * QKV_DIM;
    for (int hh = wave; hh < NH + 2 * NKV; hh += 4) {
        float x1 = (float)r0[hh * HD + lane] + (float)r1[hh * HD + lane];
        float x2 = (float)r0[hh * HD + lane + 64] + (float)r1[hh * HD + lane + 64];
        if (hh < NH + NKV) {
            float ss = x1 * x1 + x2 * x2;
            for (int o = 1; o < 64; o <<= 1) ss += __shfl_xor(ss, o);
            float inv = rsqrtf(ss * (1.0f / HD) + 1e-6f);
            const float* w = (hh < NH) ? qw : kw;
            x1 = x1 * inv * w[lane];
            x2 = x2 * inv * w[lane + 64];
            float y1 = x1 * c - x2 * s;
            float y2 = x2 * c + x1 * s;
            _Float16* dst;
            if (hh < NH) dst = Qb + ((size_t)hh * T + t) * HD;
            else         dst = Kb + ((size_t)(hh - NH) * T + t) * HD;
            dst[lane]      = (_Float16)y1;
            dst[lane + 64] = (_Float16)y2;
        } else {
            int hk = hh - NH - NKV;
            Vt[((size_t)hk * HD + lane) * T + t]      = (_Float16)x1;
            Vt[((size_t)hk * HD + lane + 64) * T + t] = (_Float16)x2;
        }
    }
}

// ---------------- Flash attention: 1024 blocks x 64 q-rows -----------------
__global__ __launch_bounds__(256, 4)
void attn(const _Float16* __restrict__ Qb, const _Float16* __restrict__ Kb,
          const _Float16* __restrict__ Vt, _Float16* __restrict__ Ob) {
    __shared__ __align__(16) _Float16 Ksm[8192];    // [64][128] col-block ^ (row&7)
    __shared__ __align__(16) _Float16 Vsm[8192];    // [128][64] col-block ^ (row&7)
    __shared__ __align__(16) _Float16 Psm[4][1024]; // per-wave [16][64] swizzled
    int b = blockIdx.x;
    int h = b & 31;
    int quarter = b >> 8;
    int i = (b & 255) >> 5;
    int qt = (quarter == 0) ? 31 - i : (quarter == 1) ? i
           : (quarter == 2) ? 23 - i : 8 + i;
    int hk = h >> 3;
    int tid = threadIdx.x, wave = tid >> 6, lane = tid & 63;
    int quad = lane >> 4, l16 = lane & 15;
    int q0 = qt * 64;
    int wbase = q0 + wave * 16;

    half8 aq[4];
    {
        const _Float16* qp = Qb + ((size_t)h * T + wbase + l16) * HD + quad * 8;
        #pragma unroll
        for (int dk = 0; dk < 4; dk++)
            aq[dk] = *(const half8*)(qp + dk * 32);
    }
    floatx4 o_acc[8] = {};
    float lpart[4] = {};

    int krow = tid >> 4;
    const _Float16* Kg = Kb + ((size_t)hk * T + krow) * HD + ((tid & 15) ^ (krow & 7)) * 8;
    int vrow = tid >> 3;
    const _Float16* Vg = Vt + ((size_t)hk * HD + vrow) * T + ((tid & 7) ^ (vrow & 7)) * 8;
    _Float16* KsmW = Ksm + wave * 512;
    _Float16* VsmW = Vsm + wave * 512;
    _Float16* PsmW = Psm[wave];

    int ntiles = qt + 1;
    for (int it = 0; it < ntiles; it++) {
        int kv0 = it * 64;
        __syncthreads();
        {
            const _Float16* kg = Kg + (size_t)kv0 * HD;
            const _Float16* vg = Vg + kv0;
            #pragma unroll
            for (int c = 0; c < 4; c++) {
                GLD16(kg + (size_t)c * (16 * HD), KsmW + c * 2048);
                GLD16(vg + (size_t)c * (32 * T), VsmW + c * 2048);
            }
        }
        __syncthreads();

        floatx4 sfr[4];
        #pragma unroll
        for (int sn = 0; sn < 4; sn++) {
            int row = sn * 16 + l16;
            int rs = row & 7;
            floatx4 a = {};
            #pragma unroll
            for (int dk = 0; dk < 4; dk++) {
                half8 kf = *(const half8*)&Ksm[row * 128 + ((dk * 4 + quad) ^ rs) * 8];
                a = __builtin_amdgcn_mfma_f32_16x16x32_f16(aq[dk], kf, a, 0, 0, 0);
            }
            sfr[sn] = a;
        }

        bool needmask = (it == ntiles - 1);
        int rq = wbase + quad * 4;
        #pragma unroll
        for (int sn = 0; sn < 4; sn++) {
            int kv = kv0 + sn * 16 + l16;
            #pragma unroll
            for (int r = 0; r < 4; r++) {
                float p = __builtin_amdgcn_exp2f(
                    __builtin_fmaf(sfr[sn][r], C2LOG, -MFIX));
                if (needmask) p = (kv <= rq + r) ? p : 0.0f;
                lpart[r] += p;
                int prow = quad * 4 + r;
                int cb = sn * 2 + (l16 >> 3);
                PsmW[prow * 64 + ((cb ^ (prow & 7)) * 8 + (l16 & 7))] = (_Float16)p;
            }
        }
        half8 ap0 = *(const half8*)&PsmW[l16 * 64 + ((quad ^ (l16 & 7)) * 8)];
        half8 ap1 = *(const half8*)&PsmW[l16 * 64 + (((4 + quad) ^ (l16 & 7)) * 8)];

        #pragma unroll
        for (int dn = 0; dn < 8; dn++) {
            int row = dn * 16 + l16;
            int rs = row & 7;
            half8 v0 = *(const half8*)&Vsm[row * 64 + ((quad ^ rs) * 8)];
            half8 v1 = *(const half8*)&Vsm[row * 64 + (((4 + quad) ^ rs) * 8)];
            o_acc[dn] = __builtin_amdgcn_mfma_f32_16x16x32_f16(ap0, v0, o_acc[dn], 0, 0, 0);
            o_acc[dn] = __builtin_amdgcn_mfma_f32_16x16x32_f16(ap1, v1, o_acc[dn], 0, 0, 0);
        }
    }

    #pragma unroll
    for (int o = 1; o < 16; o <<= 1)
        #pragma unroll
        for (int r = 0; r < 4; r++)
            lpart[r] += __shfl_xor(lpart[r], o);
    float linv[4];
    #pragma unroll
    for (int r = 0; r < 4; r++) linv[r] = 1.0f / lpart[r];
    int rowb = wbase + quad * 4;
    #pragma unroll
    for (int dn = 0; dn < 8; dn++) {
        int col = h * HD + dn * 16 + l16;
        #pragma unroll
        for (int r = 0; r < 4; r++)
            Ob[(size_t)(rowb + r) * OD + col] = (_Float16)(o_acc[dn][r] * linv[r]);
    }
}

extern "C" void kernel_launch(void* const* d_in, const int* in_sizes, int n_in,
                              void* d_out, int out_size, void* d_ws, size_t ws_size,
                              hipStream_t stream) {
    const int*   positions = (const int*)d_in[0];
    const float* hidden    = (const float*)d_in[1];
    const float* w_qkv     = (const float*)d_in[2];
    const float* w_o       = (const float*)d_in[3];
    const float* q_norm_w  = (const float*)d_in[4];
    const float* k_norm_w  = (const float*)d_in[5];
    float* out = (float*)d_out;

    const size_t MiB = 1048576;
    char* ws = (char*)d_ws;
    // live ranges (MiB): hb[0,8) wqkvb[8,28) wob[28,44) qkvp0[44,64) qkvp1[64,84)
    // Qb[84,100) Kb[100,102) Vt[102,104) Ob[104,120)
    // out partials reuse dead regions: op0[0,16) op1[44,60) op2[60,76) op3[84,100)
    _Float16* hb    = (_Float16*)(ws);
    _Float16* wqkvb = (_Float16*)(ws + 8 * MiB);
    _Float16* wob   = (_Float16*)(ws + 28 * MiB);
    _Float16* qkvp0 = (_Float16*)(ws + 44 * MiB);
    _Float16* qkvp1 = (_Float16*)(ws + 64 * MiB);
    _Float16* Qb    = (_Float16*)(ws + 84 * MiB);
    _Float16* Kb    = (_Float16*)(ws + 100 * MiB);
    _Float16* Vt    = (_Float16*)(ws + 102 * MiB);
    _Float16* Ob    = (_Float16*)(ws + 104 * MiB);
    float*    op0   = (float*)(ws);
    float*    op1   = (float*)(ws + 44 * MiB);
    float*    op2   = (float*)(ws + 60 * MiB);
    float*    op3   = (float*)(ws + 84 * MiB);

    cvt_all<<<22528, 256, 0, stream>>>(hidden, w_qkv, w_o, hb);

    // qkv partial GEMMs: split-K=2 over K=2048
    gemm_sk_h<<<dim3(QKV_DIM / 128, T / 128, 2), 256, 0, stream>>>(
        hb, wqkvb, qkvp0, qkvp1, T, QKV_DIM, HID, HID / 2);

    qkv_post<<<T, 256, 0, stream>>>(qkvp0, qkvp1, positions, q_norm_w, k_norm_w, Qb, Kb, Vt);

    attn<<<1024, 256, 0, stream>>>(Qb, Kb, Vt, Ob);

    // out projection: split-K=4 over K=4096
    gemm_sk_f<<<dim3(HID / 128, T / 128, 4), 256, 0, stream>>>(
        Ob, wob, op0, op1, op2, op3, T, HID, OD, OD / 4);
    reduce4<<<T * HID / 1024, 256, 0, stream>>>(op0, op1, op2, op3, out);
}

// Round 6
// 340.770 us; speedup vs baseline: 1.5523x; 1.0066x over previous
//
#include <hip/hip_runtime.h>
#include <math.h>

#define T 2048
#define HID 2048
#define NH 32
#define NKV 4
#define HD 128
#define QKV_DIM 5120   // (NH + 2*NKV) * HD
#define OD 4096        // NH * HD
// SCALE * log2(e): scores go straight to log2 domain
#define C2LOG 0.12751743f
#define MFIX 6.0f      // fixed softmax exponent shift (cancels in O/l)

typedef _Float16 half8 __attribute__((ext_vector_type(8)));
typedef _Float16 half4v __attribute__((ext_vector_type(4)));
typedef float floatx4 __attribute__((ext_vector_type(4)));

// async global->LDS, 16B per lane; LDS dest is wave-uniform base + lane*16
#define GLD16(gp, lp) __builtin_amdgcn_global_load_lds( \
    (const __attribute__((address_space(1))) void*)(gp), \
    (__attribute__((address_space(3))) void*)(lp), 16, 0, 0)

// ---------------- fused fp32 -> fp16 conversion (hidden, w_qkv, w_o) -------
__global__ __launch_bounds__(256)
void cvt_all(const float* __restrict__ h, const float* __restrict__ wq,
             const float* __restrict__ wo, _Float16* __restrict__ out) {
    size_t i = ((size_t)blockIdx.x * 256 + threadIdx.x) * 4;
    const float* src;
    size_t off;
    if (i < (size_t)T * HID)                        { src = h;  off = i; }
    else if (i < (size_t)T * HID + (size_t)QKV_DIM * HID)
                                                    { src = wq; off = i - (size_t)T * HID; }
    else                                            { src = wo; off = i - (size_t)T * HID - (size_t)QKV_DIM * HID; }
    float4 v = *(const float4*)(src + off);
    half4v o = { (_Float16)v.x, (_Float16)v.y, (_Float16)v.z, (_Float16)v.w };
    *(half4v*)(out + i) = o;
}

// -------- split-K GEMM (NT), fp16 partial out, BK=64 (2x 32-col panels) ----
// 128x128 tile; LDS 32KB -> 5 blocks/CU; 32 MFMA per barrier round.
__global__ __launch_bounds__(256)
void gemm_sk_h(const _Float16* __restrict__ A, const _Float16* __restrict__ B,
               _Float16* __restrict__ p0, _Float16* __restrict__ p1,
               int M, int N, int K, int KS) {
    __shared__ __align__(16) _Float16 Asm[8192];  // [2 panels][128][32]
    __shared__ __align__(16) _Float16 Bsm[8192];
    int tid = threadIdx.x;
    int wave = tid >> 6, lane = tid & 63;
    int quad = lane >> 4, l16 = lane & 15;
    int m0 = blockIdx.y * 128, n0 = blockIdx.x * 128;
    int koff = blockIdx.z * KS;
    _Float16* C = blockIdx.z ? p1 : p0;
    int wm = (wave >> 1) * 64, wn = (wave & 1) * 64;
    const _Float16* Ag = A + (size_t)(m0 + (tid >> 2)) * K + koff + (tid & 3) * 8;
    const _Float16* Bg = B + (size_t)(n0 + (tid >> 2)) * K + koff + (tid & 3) * 8;
    size_t row64 = (size_t)64 * K;
    _Float16* AsmW = Asm + wave * 512;
    _Float16* BsmW = Bsm + wave * 512;
    floatx4 acc[4][4] = {};
    for (int k0 = 0; k0 < KS; k0 += 64) {
        __syncthreads();
        GLD16(Ag, AsmW);                    // panel 0, rows 0-63
        GLD16(Ag + row64, AsmW + 2048);     // panel 0, rows 64-127
        GLD16(Ag + 32, AsmW + 4096);        // panel 1, rows 0-63
        GLD16(Ag + row64 + 32, AsmW + 6144);
        GLD16(Bg, BsmW);
        GLD16(Bg + row64, BsmW + 2048);
        GLD16(Bg + 32, BsmW + 4096);
        GLD16(Bg + row64 + 32, BsmW + 6144);
        Ag += 64; Bg += 64;
        __syncthreads();
        #pragma unroll
        for (int p = 0; p < 2; p++) {
            half8 af[4], bf[4];
            #pragma unroll
            for (int i = 0; i < 4; i++)
                af[i] = *(const half8*)&Asm[p * 4096 + (wm + i * 16 + l16) * 32 + quad * 8];
            #pragma unroll
            for (int j = 0; j < 4; j++)
                bf[j] = *(const half8*)&Bsm[p * 4096 + (wn + j * 16 + l16) * 32 + quad * 8];
            #pragma unroll
            for (int i = 0; i < 4; i++)
                #pragma unroll
                for (int j = 0; j < 4; j++)
                    acc[i][j] = __builtin_amdgcn_mfma_f32_16x16x32_f16(af[i], bf[j], acc[i][j], 0, 0, 0);
        }
    }
    #pragma unroll
    for (int i = 0; i < 4; i++) {
        int row = m0 + wm + i * 16 + quad * 4;
        #pragma unroll
        for (int j = 0; j < 4; j++) {
            int col = n0 + wn + j * 16 + l16;
            #pragma unroll
            for (int r = 0; r < 4; r++)
                C[(size_t)(row + r) * N + col] = (_Float16)acc[i][j][r];
        }
    }
}

// -------- split-K GEMM (NT), fp16 partials x4, BK=64 -----------------------
__global__ __launch_bounds__(256)
void gemm_sk_f(const _Float16* __restrict__ A, const _Float16* __restrict__ B,
               _Float16* __restrict__ p0, _Float16* __restrict__ p1,
               _Float16* __restrict__ p2, _Float16* __restrict__ p3,
               int M, int N, int K, int KS) {
    __shared__ __align__(16) _Float16 Asm[8192];
    __shared__ __align__(16) _Float16 Bsm[8192];
    int tid = threadIdx.x;
    int wave = tid >> 6, lane = tid & 63;
    int quad = lane >> 4, l16 = lane & 15;
    int m0 = blockIdx.y * 128, n0 = blockIdx.x * 128;
    int bz = blockIdx.z;
    int koff = bz * KS;
    _Float16* C = (bz == 0) ? p0 : (bz == 1) ? p1 : (bz == 2) ? p2 : p3;
    int wm = (wave >> 1) * 64, wn = (wave & 1) * 64;
    const _Float16* Ag = A + (size_t)(m0 + (tid >> 2)) * K + koff + (tid & 3) * 8;
    const _Float16* Bg = B + (size_t)(n0 + (tid >> 2)) * K + koff + (tid & 3) * 8;
    size_t row64 = (size_t)64 * K;
    _Float16* AsmW = Asm + wave * 512;
    _Float16* BsmW = Bsm + wave * 512;
    floatx4 acc[4][4] = {};
    for (int k0 = 0; k0 < KS; k0 += 64) {
        __syncthreads();
        GLD16(Ag, AsmW);
        GLD16(Ag + row64, AsmW + 2048);
        GLD16(Ag + 32, AsmW + 4096);
        GLD16(Ag + row64 + 32, AsmW + 6144);
        GLD16(Bg, BsmW);
        GLD16(Bg + row64, BsmW + 2048);
        GLD16(Bg + 32, BsmW + 4096);
        GLD16(Bg + row64 + 32, BsmW + 6144);
        Ag += 64; Bg += 64;
        __syncthreads();
        #pragma unroll
        for (int p = 0; p < 2; p++) {
            half8 af[4], bf[4];
            #pragma unroll
            for (int i = 0; i < 4; i++)
                af[i] = *(const half8*)&Asm[p * 4096 + (wm + i * 16 + l16) * 32 + quad * 8];
            #pragma unroll
            for (int j = 0; j < 4; j++)
                bf[j] = *(const half8*)&Bsm[p * 4096 + (wn + j * 16 + l16) * 32 + quad * 8];
            #pragma unroll
            for (int i = 0; i < 4; i++)
                #pragma unroll
                for (int j = 0; j < 4; j++)
                    acc[i][j] = __builtin_amdgcn_mfma_f32_16x16x32_f16(af[i], bf[j], acc[i][j], 0, 0, 0);
        }
    }
    #pragma unroll
    for (int i = 0; i < 4; i++) {
        int row = m0 + wm + i * 16 + quad * 4;
        #pragma unroll
        for (int j = 0; j < 4; j++) {
            int col = n0 + wn + j * 16 + l16;
            #pragma unroll
            for (int r = 0; r < 4; r++)
                C[(size_t)(row + r) * N + col] = (_Float16)acc[i][j][r];
        }
    }
}

// ---------------- reduce 4 fp16 partials -> fp32 out ------------------------
__global__ __launch_bounds__(256)
void reduce4(const _Float16* __restrict__ p0, const _Float16* __restrict__ p1,
             const _Float16* __restrict__ p2, const _Float16* __restrict__ p3,
             float* __restrict__ out) {
    size_t i = ((size_t)blockIdx.x * 256 + threadIdx.x) * 4;
    half4v a = *(const half4v*)(p0 + i);
    half4v b = *(const half4v*)(p1 + i);
    half4v c = *(const half4v*)(p2 + i);
    half4v d = *(const half4v*)(p3 + i);
    float4 o = { (float)a.x + (float)b.x + (float)c.x + (float)d.x,
                 (float)a.y + (float)b.y + (float)c.y + (float)d.y,
                 (float)a.z + (float)b.z + (float)c.z + (float)d.z,
                 (float)a.w + (float)b.w + (float)c.w + (float)d.w };
    *(float4*)(out + i) = o;
}

// ---------------- RMSNorm + RoPE + reorder (sums 2 fp16 partials) ----------
__global__ __launch_bounds__(256)
void qkv_post(const _Float16* __restrict__ qp0, const _Float16* __restrict__ qp1,
              const int* __restrict__ positions,
              const float* __restrict__ qw, const float* __restrict__ kw,
              _Float16* __restrict__ Qb, _Float16* __restrict__ Kb,
              _Float16* __restrict__ Vt) {
    int t = blockIdx.x;
    int wave = threadIdx.x >> 6, lane = threadIdx.x & 63;
    float pos = (float)positions[t];
    float f = exp2f(-(float)lane * (19.9315685693241741f / 64.0f));
    float ang = pos * f;
    float s = sinf(ang), c = cosf(ang);
    const _Float16* r0 = qp0 + (size_t)t * QKV_DIM;
    const _Float16* r1 = qp1 + (size_t)t * QKV_DIM;
    for (int hh = wave; hh < NH + 2 * NKV; hh += 4) {
        float x1 = (float)r0[hh * HD + lane] + (float)r1[hh * HD + lane];
        float x2 = (float)r0[hh * HD + lane + 64] + (float)r1[hh * HD + lane + 64];
        if (hh < NH + NKV) {
            float ss = x1 * x1 + x2 * x2;
            for (int o = 1; o < 64; o <<= 1) ss += __shfl_xor(ss, o);
            float inv = rsqrtf(ss * (1.0f / HD) + 1e-6f);
            const float* w = (hh < NH) ? qw : kw;
            x1 = x1 * inv * w[lane];
            x2 = x2 * inv * w[lane + 64];
            float y1 = x1 * c - x2 * s;
            float y2 = x2 * c + x1 * s;
            _Float16* dst;
            if (hh < NH) dst = Qb + ((size_t)hh * T + t) * HD;
            else         dst = Kb + ((size_t)(hh - NH) * T + t) * HD;
            dst[lane]      = (_Float16)y1;
            dst[lane + 64] = (_Float16)y2;
        } else {
            int hk = hh - NH - NKV;
            Vt[((size_t)hk * HD + lane) * T + t]      = (_Float16)x1;
            Vt[((size_t)hk * HD + lane + 64) * T + t] = (_Float16)x2;
        }
    }
}

// ---------------- Flash attention: 1024 blocks x 64 q-rows -----------------
__global__ __launch_bounds__(256, 4)
void attn(const _Float16* __restrict__ Qb, const _Float16* __restrict__ Kb,
          const _Float16* __restrict__ Vt, _Float16* __restrict__ Ob) {
    __shared__ __align__(16) _Float16 Ksm[8192];    // [64][128] col-block ^ (row&7)
    __shared__ __align__(16) _Float16 Vsm[8192];    // [128][64] col-block ^ (row&7)
    __shared__ __align__(16) _Float16 Psm[4][1024]; // per-wave [16][64] swizzled
    int b = blockIdx.x;
    int h = b & 31;
    int quarter = b >> 8;
    int i = (b & 255) >> 5;
    int qt = (quarter == 0) ? 31 - i : (quarter == 1) ? i
           : (quarter == 2) ? 23 - i : 8 + i;
    int hk = h >> 3;
    int tid = threadIdx.x, wave = tid >> 6, lane = tid & 63;
    int quad = lane >> 4, l16 = lane & 15;
    int q0 = qt * 64;
    int wbase = q0 + wave * 16;

    half8 aq[4];
    {
        const _Float16* qp = Qb + ((size_t)h * T + wbase + l16) * HD + quad * 8;
        #pragma unroll
        for (int dk = 0; dk < 4; dk++)
            aq[dk] = *(const half8*)(qp + dk * 32);
    }
    floatx4 o_acc[8] = {};
    float lpart[4] = {};

    int krow = tid >> 4;
    const _Float16* Kg = Kb + ((size_t)hk * T + krow) * HD + ((tid & 15) ^ (krow & 7)) * 8;
    int vrow = tid >> 3;
    const _Float16* Vg = Vt + ((size_t)hk * HD + vrow) * T + ((tid & 7) ^ (vrow & 7)) * 8;
    _Float16* KsmW = Ksm + wave * 512;
    _Float16* VsmW = Vsm + wave * 512;
    _Float16* PsmW = Psm[wave];

    int ntiles = qt + 1;
    for (int it = 0; it < ntiles; it++) {
        int kv0 = it * 64;
        __syncthreads();
        {
            const _Float16* kg = Kg + (size_t)kv0 * HD;
            const _Float16* vg = Vg + kv0;
            #pragma unroll
            for (int c = 0; c < 4; c++) {
                GLD16(kg + (size_t)c * (16 * HD), KsmW + c * 2048);
                GLD16(vg + (size_t)c * (32 * T), VsmW + c * 2048);
            }
        }
        __syncthreads();

        floatx4 sfr[4];
        #pragma unroll
        for (int sn = 0; sn < 4; sn++) {
            int row = sn * 16 + l16;
            int rs = row & 7;
            floatx4 a = {};
            #pragma unroll
            for (int dk = 0; dk < 4; dk++) {
                half8 kf = *(const half8*)&Ksm[row * 128 + ((dk * 4 + quad) ^ rs) * 8];
                a = __builtin_amdgcn_mfma_f32_16x16x32_f16(aq[dk], kf, a, 0, 0, 0);
            }
            sfr[sn] = a;
        }

        bool needmask = (it == ntiles - 1);
        int rq = wbase + quad * 4;
        #pragma unroll
        for (int sn = 0; sn < 4; sn++) {
            int kv = kv0 + sn * 16 + l16;
            #pragma unroll
            for (int r = 0; r < 4; r++) {
                float p = __builtin_amdgcn_exp2f(
                    __builtin_fmaf(sfr[sn][r], C2LOG, -MFIX));
                if (needmask) p = (kv <= rq + r) ? p : 0.0f;
                lpart[r] += p;
                int prow = quad * 4 + r;
                int cb = sn * 2 + (l16 >> 3);
                PsmW[prow * 64 + ((cb ^ (prow & 7)) * 8 + (l16 & 7))] = (_Float16)p;
            }
        }
        half8 ap0 = *(const half8*)&PsmW[l16 * 64 + ((quad ^ (l16 & 7)) * 8)];
        half8 ap1 = *(const half8*)&PsmW[l16 * 64 + (((4 + quad) ^ (l16 & 7)) * 8)];

        #pragma unroll
        for (int dn = 0; dn < 8; dn++) {
            int row = dn * 16 + l16;
            int rs = row & 7;
            half8 v0 = *(const half8*)&Vsm[row * 64 + ((quad ^ rs) * 8)];
            half8 v1 = *(const half8*)&Vsm[row * 64 + (((4 + quad) ^ rs) * 8)];
            o_acc[dn] = __builtin_amdgcn_mfma_f32_16x16x32_f16(ap0, v0, o_acc[dn], 0, 0, 0);
            o_acc[dn] = __builtin_amdgcn_mfma_f32_16x16x32_f16(ap1, v1, o_acc[dn], 0, 0, 0);
        }
    }

    #pragma unroll
    for (int o = 1; o < 16; o <<= 1)
        #pragma unroll
        for (int r = 0; r < 4; r++)
            lpart[r] += __shfl_xor(lpart[r], o);
    float linv[4];
    #pragma unroll
    for (int r = 0; r < 4; r++) linv[r] = 1.0f / lpart[r];
    int rowb = wbase + quad * 4;
    #pragma unroll
    for (int dn = 0; dn < 8; dn++) {
        int col = h * HD + dn * 16 + l16;
        #pragma unroll
        for (int r = 0; r < 4; r++)
            Ob[(size_t)(rowb + r) * OD + col] = (_Float16)(o_acc[dn][r] * linv[r]);
    }
}

extern "C" void kernel_launch(void* const* d_in, const int* in_sizes, int n_in,
                              void* d_out, int out_size, void* d_ws, size_t ws_size,
                              hipStream_t stream) {
    const int*   positions = (const int*)d_in[0];
    const float* hidden    = (const float*)d_in[1];
    const float* w_qkv     = (const float*)d_in[2];
    const float* w_o       = (const float*)d_in[3];
    const float* q_norm_w  = (const float*)d_in[4];
    const float* k_norm_w  = (const float*)d_in[5];
    float* out = (float*)d_out;

    const size_t MiB = 1048576;
    char* ws = (char*)d_ws;
    // live ranges (MiB): hb[0,8) wqkvb[8,28) wob[28,44) qkvp0[44,64) qkvp1[64,84)
    // Qb[84,100) Kb[100,102) Vt[102,104) Ob[104,120)
    // out fp16 partials (8.4 MiB ea) reuse dead regions: [0,9) [9,18) [44,53) [53,62)
    _Float16* hb    = (_Float16*)(ws);
    _Float16* wqkvb = (_Float16*)(ws + 8 * MiB);
    _Float16* wob   = (_Float16*)(ws + 28 * MiB);
    _Float16* qkvp0 = (_Float16*)(ws + 44 * MiB);
    _Float16* qkvp1 = (_Float16*)(ws + 64 * MiB);
    _Float16* Qb    = (_Float16*)(ws + 84 * MiB);
    _Float16* Kb    = (_Float16*)(ws + 100 * MiB);
    _Float16* Vt    = (_Float16*)(ws + 102 * MiB);
    _Float16* Ob    = (_Float16*)(ws + 104 * MiB);
    _Float16* op0   = (_Float16*)(ws);
    _Float16* op1   = (_Float16*)(ws + 9 * MiB);
    _Float16* op2   = (_Float16*)(ws + 44 * MiB);
    _Float16* op3   = (_Float16*)(ws + 53 * MiB);

    cvt_all<<<22528, 256, 0, stream>>>(hidden, w_qkv, w_o, hb);

    // qkv partial GEMMs: split-K=2 over K=2048
    gemm_sk_h<<<dim3(QKV_DIM / 128, T / 128, 2), 256, 0, stream>>>(
        hb, wqkvb, qkvp0, qkvp1, T, QKV_DIM, HID, HID / 2);

    qkv_post<<<T, 256, 0, stream>>>(qkvp0, qkvp1, positions, q_norm_w, k_norm_w, Qb, Kb, Vt);

    attn<<<1024, 256, 0, stream>>>(Qb, Kb, Vt, Ob);

    // out projection: split-K=4 over K=4096
    gemm_sk_f<<<dim3(HID / 128, T / 128, 4), 256, 0, stream>>>(
        Ob, wob, op0, op1, op2, op3, T, HID, OD, OD / 4);
    reduce4<<<T * HID / 1024, 256, 0, stream>>>(op0, op1, op2, op3, out);
}